// Round 6
// baseline (1901.936 us; speedup 1.0000x reference)
//
#include <hip/hip_runtime.h>
#include <hip/hip_fp16.h>

#define NLAYERS 4
#define BSHIFT 9          // rows per bucket = 512
#define MAXNB 4096        // max buckets supported (NCAT <= 2M)

// ---------------- zero fill ----------------
__global__ void zero_int_kernel(int* __restrict__ p, long n) {
    long i = (long)blockIdx.x * 256 + threadIdx.x;
    long stride = (long)gridDim.x * 256;
    for (; i < n; i += stride) p[i] = 0;
}

__device__ __forceinline__ float fast_tanh(float y) {
    y = fminf(fmaxf(y, -15.f), 15.f);
    float t = __expf(2.f * y);
    return (t - 1.f) / (t + 1.f);
}

// ================= two-level counting-sort CSR build =================
// concatenated dst space: [0,NT) rel0 | [NT,NT+NA) rel1 | [NT+NA,NCAT) rel2
__device__ __forceinline__ int edge_row(const int* ei_in, const int* ei_out, const int* ei_sp,
                                        int E_IN, int E_OUT, int E_SP, int NT, int NA,
                                        int e, int* src) {
    if (e < E_IN) { *src = ei_in[e]; return ei_in[E_IN + e]; }
    if (e < E_IN + E_OUT) { int i = e - E_IN; *src = ei_out[i]; return NT + ei_out[E_OUT + i]; }
    int i = e - E_IN - E_OUT; *src = ei_sp[i]; return NT + NA + ei_sp[E_SP + i];
}

__global__ void bucket_hist_kernel(const int* __restrict__ ei_in, const int* __restrict__ ei_out,
                                   const int* __restrict__ ei_sp, int E_IN, int E_OUT, int E_SP,
                                   int NT, int NA, int* __restrict__ bcnt, int NB, int E_TOT) {
    __shared__ int h[MAXNB];
    int tid = threadIdx.x;
    for (int i = tid; i < NB; i += 256) h[i] = 0;
    __syncthreads();
    int stride = gridDim.x * 256;
    for (int e = blockIdx.x * 256 + tid; e < E_TOT; e += stride) {
        int s;
        int row = edge_row(ei_in, ei_out, ei_sp, E_IN, E_OUT, E_SP, NT, NA, e, &s);
        atomicAdd(&h[row >> BSHIFT], 1);
    }
    __syncthreads();
    for (int i = tid; i < NB; i += 256) {
        int v = h[i];
        if (v) atomicAdd(&bcnt[i], v);
    }
}

// single block, 1024 threads, 4 elems/thread -> NB <= 4096
__global__ void bucket_scan_kernel(const int* __restrict__ bcnt, int* __restrict__ bstart,
                                   int* __restrict__ bcur, int NB, int E) {
    __shared__ int lds[1024];
    int tid = threadIdx.x;
    int v[4];
    int s = 0;
    #pragma unroll
    for (int j = 0; j < 4; j++) {
        int i = tid * 4 + j;
        v[j] = (i < NB) ? bcnt[i] : 0;
        s += v[j];
    }
    lds[tid] = s;
    __syncthreads();
    for (int off = 1; off < 1024; off <<= 1) {
        int t = (tid >= off) ? lds[tid - off] : 0;
        __syncthreads();
        lds[tid] += t;
        __syncthreads();
    }
    int run = lds[tid] - s;
    #pragma unroll
    for (int j = 0; j < 4; j++) {
        int i = tid * 4 + j;
        if (i < NB) { bstart[i] = run; bcur[i] = run; }
        run += v[j];
    }
    if (tid == 0) bstart[NB] = E;
}

__global__ void pair_scatter_kernel(const int* __restrict__ ei_in, const int* __restrict__ ei_out,
                                    const int* __restrict__ ei_sp, int E_IN, int E_OUT, int E_SP,
                                    int NT, int NA, int* __restrict__ bcur,
                                    int2* __restrict__ pairs, int E_TOT) {
    int e = blockIdx.x * 256 + threadIdx.x;
    if (e >= E_TOT) return;
    int s;
    int row = edge_row(ei_in, ei_out, ei_sp, E_IN, E_OUT, E_SP, NT, NA, e, &s);
    int pos = atomicAdd(&bcur[row >> BSHIFT], 1);
    pairs[pos] = make_int2(row, s);
}

// one block per bucket: LDS counting sort of 512 rows
__global__ void bucket_sort_kernel(const int2* __restrict__ pairs, const int* __restrict__ bstart,
                                   int* __restrict__ rowptr, int* __restrict__ col,
                                   int NCAT, int E_TOT) {
    __shared__ int cnt[512];
    __shared__ int sc[256];
    int tid = threadIdx.x;
    int b = blockIdx.x;
    int row0 = b << BSHIFT;
    int bs = bstart[b], be = bstart[b + 1];
    cnt[tid] = 0; cnt[tid + 256] = 0;
    __syncthreads();
    for (int e = bs + tid; e < be; e += 256) {
        atomicAdd(&cnt[pairs[e].x - row0], 1);
    }
    __syncthreads();
    // exclusive scan of cnt[512] via 256 threads (2 elems each)
    int a0 = cnt[2 * tid], a1 = cnt[2 * tid + 1];
    int s = a0 + a1;
    sc[tid] = s;
    __syncthreads();
    for (int off = 1; off < 256; off <<= 1) {
        int t = (tid >= off) ? sc[tid - off] : 0;
        __syncthreads();
        sc[tid] += t;
        __syncthreads();
    }
    int exclp = sc[tid] - s;
    cnt[2 * tid] = exclp;
    cnt[2 * tid + 1] = exclp + a0;
    __syncthreads();
    // rowptr for this bucket's rows (coalesced)
    #pragma unroll
    for (int j = 0; j < 2; j++) {
        int lr = tid + j * 256;
        int row = row0 + lr;
        if (row < NCAT) rowptr[row] = bs + cnt[lr];
    }
    if (b == 0 && tid == 0) rowptr[NCAT] = E_TOT;
    __syncthreads();
    // scatter src into dense col segment
    for (int e = bs + tid; e < be; e += 256) {
        int2 p = pairs[e];
        int pos = bs + atomicAdd(&cnt[p.x - row0], 1);
        col[pos] = p.y;
    }
}

// ================= fused encoder + layer-0 projection =================
__global__ void encproj_addr_kernel(const float* __restrict__ x,
                                    const float* __restrict__ We, const float* __restrict__ be,
                                    const float* __restrict__ Wp, const float* __restrict__ bp,
                                    const float* __restrict__ a0, const float* __restrict__ a1,
                                    float* __restrict__ xa, __half* __restrict__ h,
                                    float* __restrict__ o0, float* __restrict__ o1, int n) {
    __shared__ float sWe[53 * 32];
    __shared__ float sW[1024];
    __shared__ float sv[3][32];
    __shared__ float sbp[32];
    __shared__ float sx[8][56];
    __shared__ float sh[8][33];
    int tid = threadIdx.x;
    for (int i = tid; i < 53 * 32; i += 256) sWe[i] = We[i];
    for (int i = tid; i < 1024; i += 256) sW[i] = Wp[i];
    if (tid < 32) { sv[0][tid] = be[tid]; sv[1][tid] = a0[tid]; sv[2][tid] = a1[tid]; sbp[tid] = bp[tid]; }
    int local = tid >> 5, f = tid & 31;
    int node = blockIdx.x * 8 + local;
    if (node < n) {
        for (int k = f; k < 53; k += 32) sx[local][k] = x[(size_t)node * 53 + k];
    }
    __syncthreads();
    float xe = 0.f;
    if (node < n) {
        float acc = sv[0][f];
        for (int k = 0; k < 53; k++) acc += sx[local][k] * sWe[k * 32 + f];
        xe = fmaxf(acc, 0.f);
        xa[(size_t)node * 32 + f] = xe;
    }
    sh[local][f] = xe;
    __syncthreads();
    float accp = 0.f;
    if (node < n) {
        accp = sbp[f];
        #pragma unroll
        for (int k = 0; k < 32; k++) accp += sh[local][k] * sW[k * 32 + f];
        h[(size_t)node * 32 + f] = __float2half(accp);
    }
    __syncthreads();
    sh[local][f] = accp;
    __syncthreads();
    if (node < n && f < 8) {
        int vec = f >> 2, head = f & 3;
        const float* av = sv[1 + vec];
        float dsum = 0.f;
        #pragma unroll
        for (int dd = 0; dd < 8; dd++) dsum += sh[local][head * 8 + dd] * av[head * 8 + dd];
        (vec == 0 ? o0 : o1)[(size_t)node * 4 + head] = dsum;
    }
}

__global__ void encproj_tx_kernel(const float* __restrict__ x,
                                  const float* __restrict__ We, const float* __restrict__ be,
                                  const float* __restrict__ Wp, const float* __restrict__ bp,
                                  const float* __restrict__ a0, const float* __restrict__ a1,
                                  const float* __restrict__ a2, const float* __restrict__ a3,
                                  float* __restrict__ xt, __half* __restrict__ h,
                                  float* __restrict__ o0, float* __restrict__ o1,
                                  float* __restrict__ o2, float* __restrict__ o3, int n) {
    __shared__ float sWe[6 * 32];
    __shared__ float sW[1024];
    __shared__ float sv[5][32];
    __shared__ float sbp[32];
    __shared__ float sx[8][8];
    __shared__ float sh[8][33];
    int tid = threadIdx.x;
    for (int i = tid; i < 6 * 32; i += 256) sWe[i] = We[i];
    for (int i = tid; i < 1024; i += 256) sW[i] = Wp[i];
    if (tid < 32) {
        sv[0][tid] = be[tid]; sv[1][tid] = a0[tid]; sv[2][tid] = a1[tid];
        sv[3][tid] = a2[tid]; sv[4][tid] = a3[tid]; sbp[tid] = bp[tid];
    }
    int local = tid >> 5, f = tid & 31;
    int node = blockIdx.x * 8 + local;
    if (node < n && f < 6) sx[local][f] = x[(size_t)node * 6 + f];
    __syncthreads();
    float xe = 0.f;
    if (node < n) {
        float acc = sv[0][f];
        #pragma unroll
        for (int k = 0; k < 6; k++) acc += sx[local][k] * sWe[k * 32 + f];
        xe = fmaxf(acc, 0.f);
        xt[(size_t)node * 32 + f] = xe;
    }
    sh[local][f] = xe;
    __syncthreads();
    float accp = 0.f;
    if (node < n) {
        accp = sbp[f];
        #pragma unroll
        for (int k = 0; k < 32; k++) accp += sh[local][k] * sW[k * 32 + f];
        h[(size_t)node * 32 + f] = __float2half(accp);
    }
    __syncthreads();
    sh[local][f] = accp;
    __syncthreads();
    if (node < n && f < 16) {
        int vec = f >> 2, head = f & 3;
        const float* av = sv[1 + vec];
        float dsum = 0.f;
        #pragma unroll
        for (int dd = 0; dd < 8; dd++) dsum += sh[local][head * 8 + dd] * av[head * 8 + dd];
        float* op = vec == 0 ? o0 : vec == 1 ? o1 : vec == 2 ? o2 : o3;
        op[(size_t)node * 4 + head] = dsum;
    }
}

// ================= merged CSR aggregation (all rels) + fused semantic score =================
__global__ void agg_all_kernel(
    const int* __restrict__ rowptr, const int* __restrict__ col,
    const __half* __restrict__ h_a, const __half* __restrict__ h_t,
    const float* __restrict__ asrc0, const float* __restrict__ adst0,
    const float* __restrict__ asrc1, const float* __restrict__ adst1,
    const float* __restrict__ asrc2, const float* __restrict__ adst2,
    __half* __restrict__ agg_t0, __half* __restrict__ agg_a, __half* __restrict__ agg_t2,
    const float* __restrict__ kw, const float* __restrict__ kb, const float* __restrict__ q,
    float* __restrict__ scoreOut, int NT, int NA, int mode, int nRows) {
    __shared__ float sW[1024];
    __shared__ float sb[32];
    __shared__ float sq[32];
    __shared__ float sScore[2];
    int tid = threadIdx.x;
    bool doScore = (mode != 2);
    if (doScore) {
        for (int i = tid; i < 1024; i += 256) sW[i] = kw[i];
        if (tid < 32) { sb[tid] = kb[tid]; sq[tid] = q[tid]; }
        if (tid < 2) sScore[tid] = 0.f;
        __syncthreads();
    }
    int lane = tid & 15;
    int head = lane >> 2, f0 = lane * 2;
    long stride = (long)gridDim.x * 16;
    for (long gi = (long)blockIdx.x * 16 + (tid >> 4); gi < (long)nRows; gi += stride) {
        int row;
        if (mode == 0) row = (int)gi;
        else if (mode == 1) row = (gi < NT) ? (int)gi : (int)(gi + NA);
        else row = NT + (int)gi;
        int rel, dst;
        const __half* h; const float* asrc; const float* adp; __half* agg;
        if (row < NT)           { rel = 0; dst = row;           h = h_a; asrc = asrc0; adp = adst0; agg = agg_t0; }
        else if (row < NT + NA) { rel = 1; dst = row - NT;      h = h_t; asrc = asrc1; adp = adst1; agg = agg_a; }
        else                    { rel = 2; dst = row - NT - NA; h = h_t; asrc = asrc2; adp = adst2; agg = agg_t2; }
        float ad = adp[(size_t)dst * 4 + head];
        int e0 = rowptr[row], e1 = rowptr[row + 1];
        float accx = 0.f, accy = 0.f, den = 0.f;
        for (int e = e0; e < e1; e++) {
            int s = col[e];
            float t = asrc[(size_t)s * 4 + head] + ad;
            t = t > 0.f ? t : 0.2f * t;
            float ex = __expf(t);
            den += ex;
            float2 hf = __half22float2(*(const __half2*)(h + (size_t)s * 32 + f0));
            accx += ex * hf.x; accy += ex * hf.y;
        }
        float r = 1.f / (den + 1e-16f);
        float vx = accx * r, vy = accy * r;
        __half2 o; o.x = __float2half(vx); o.y = __float2half(vy);
        *(__half2*)(agg + (size_t)dst * 32 + f0) = o;
        if (doScore && rel != 1) {
            float r0 = fmaxf(vx, 0.f), r1 = fmaxf(vy, 0.f);
            float y0 = sb[f0], y1 = sb[f0 + 1];
            #pragma unroll
            for (int k = 0; k < 16; k++) {
                float rx = __shfl(r0, k, 16);
                float ry = __shfl(r1, k, 16);
                y0 += rx * sW[(2 * k) * 32 + f0]     + ry * sW[(2 * k + 1) * 32 + f0];
                y1 += rx * sW[(2 * k) * 32 + f0 + 1] + ry * sW[(2 * k + 1) * 32 + f0 + 1];
            }
            float sacc = sq[f0] * fast_tanh(y0) + sq[f0 + 1] * fast_tanh(y1);
            #pragma unroll
            for (int m = 1; m < 16; m <<= 1) sacc += __shfl_xor(sacc, m, 16);
            if (lane == 0) atomicAdd(&sScore[rel == 2 ? 1 : 0], sacc);
        }
    }
    if (doScore) {
        __syncthreads();
        if (tid < 2) unsafeAtomicAdd(scoreOut + tid, sScore[tid]);
    }
}

// ================= fused combine(layer l) + projection(layer l+1) =================
__global__ void combineproj_kernel(
    const __half* __restrict__ agg_a, const __half* __restrict__ agg_t0, const __half* __restrict__ agg_t2,
    float* __restrict__ xa, float* __restrict__ xt,
    const float* __restrict__ ln_ag, const float* __restrict__ ln_ab,
    const float* __restrict__ ln_tg, const float* __restrict__ ln_tb,
    const float* __restrict__ scores, float invNT,
    const float* __restrict__ Wa, const float* __restrict__ Ba,
    const float* __restrict__ Wt, const float* __restrict__ Bt,
    const float* __restrict__ as0, const float* __restrict__ ad1,
    const float* __restrict__ as1, const float* __restrict__ ad0,
    const float* __restrict__ as2, const float* __restrict__ ad2,
    __half* __restrict__ h_a, __half* __restrict__ h_t,
    float* __restrict__ o_as0, float* __restrict__ o_ad1,
    float* __restrict__ o_as1, float* __restrict__ o_ad0,
    float* __restrict__ o_as2, float* __restrict__ o_ad2,
    int NA_, int NT_, int nbA8, int lastProj) {
    __shared__ float sW[1024];
    __shared__ float sv[5][32];
    __shared__ float sbp[32];
    __shared__ float sh[8][33];
    int tid = threadIdx.x;
    bool isA = blockIdx.x < nbA8;
    const float* W = isA ? Wa : Wt;
    for (int i = tid; i < 1024; i += 256) sW[i] = W[i];
    if (tid < 32) {
        sbp[tid] = (isA ? Ba : Bt)[tid];
        sv[1][tid] = (isA ? as0 : as1)[tid];
        sv[2][tid] = (isA ? ad1 : ad0)[tid];
        if (!isA) { sv[3][tid] = as2[tid]; sv[4][tid] = ad2[tid]; }
    }
    int local = tid >> 5, f = tid & 31;
    int n = isA ? NA_ : NT_;
    int node = (isA ? blockIdx.x : blockIdx.x - nbA8) * 8 + local;
    float ln = 0.f;
    if (node < n) {
        float v;
        if (isA) {
            float a = __half2float(agg_a[(size_t)node * 32 + f]);
            v = fmaxf(a, 0.f) + xa[(size_t)node * 32 + f];
        } else {
            float s0 = scores[0] * invNT, s2 = scores[1] * invNT;
            float mx = fmaxf(s0, s2);
            float e0 = __expf(s0 - mx), e2 = __expf(s2 - mx);
            float inv_s = 1.f / (e0 + e2);
            float w0 = e0 * inv_s, w2 = e2 * inv_s;
            float a0 = fmaxf(__half2float(agg_t0[(size_t)node * 32 + f]), 0.f);
            float a2 = fmaxf(__half2float(agg_t2[(size_t)node * 32 + f]), 0.f);
            v = fmaxf(w0 * a0 + w2 * a2, 0.f) + xt[(size_t)node * 32 + f];
        }
        float m = v;
        #pragma unroll
        for (int mask = 1; mask < 32; mask <<= 1) m += __shfl_xor(m, mask, 64);
        m *= (1.f / 32.f);
        float d = v - m;
        float var = d * d;
        #pragma unroll
        for (int mask = 1; mask < 32; mask <<= 1) var += __shfl_xor(var, mask, 64);
        var *= (1.f / 32.f);
        float inv = 1.f / sqrtf(var + 1e-5f);
        ln = d * inv * (isA ? ln_ag : ln_tg)[f] + (isA ? ln_ab : ln_tb)[f];
        if (isA || !lastProj) (isA ? xa : xt)[(size_t)node * 32 + f] = ln;
    }
    sh[local][f] = ln;
    __syncthreads();
    float accp = 0.f;
    if (node < n) {
        accp = sbp[f];
        #pragma unroll
        for (int k = 0; k < 32; k++) accp += sh[local][k] * sW[k * 32 + f];
        if (!isA || !lastProj) (isA ? h_a : h_t)[(size_t)node * 32 + f] = __float2half(accp);
    }
    __syncthreads();
    sh[local][f] = accp;
    __syncthreads();
    int nvec = isA ? 8 : 16;
    if (node < n && f < nvec) {
        int vec = f >> 2, head = f & 3;
        bool need = !lastProj || (isA ? (vec == 1) : (vec == 0));
        if (need) {
            const float* av = sv[1 + vec];
            float dsum = 0.f;
            #pragma unroll
            for (int dd = 0; dd < 8; dd++) dsum += sh[local][head * 8 + dd] * av[head * 8 + dd];
            float* op;
            if (isA) op = vec == 0 ? o_as0 : o_ad1;
            else op = vec == 0 ? o_as1 : vec == 1 ? o_ad0 : vec == 2 ? o_as2 : o_ad2;
            op[(size_t)node * 4 + head] = dsum;
        }
    }
}

// ================= layer-3 combine_addr + output head =================
__global__ void combine_final_kernel(const __half* __restrict__ agg_a, const float* __restrict__ xa,
                                     const float* __restrict__ g, const float* __restrict__ bt,
                                     const float* __restrict__ lw, const float* __restrict__ lb,
                                     float* __restrict__ out, int n) {
    int tid = threadIdx.x;
    int local = tid >> 5, f = tid & 31;
    int node = blockIdx.x * 8 + local;
    if (node >= n) return;
    float a = __half2float(agg_a[(size_t)node * 32 + f]);
    float v = fmaxf(a, 0.f) + xa[(size_t)node * 32 + f];
    float m = v;
    #pragma unroll
    for (int mask = 1; mask < 32; mask <<= 1) m += __shfl_xor(m, mask, 64);
    m *= (1.f / 32.f);
    float d = v - m;
    float var = d * d;
    #pragma unroll
    for (int mask = 1; mask < 32; mask <<= 1) var += __shfl_xor(var, mask, 64);
    var *= (1.f / 32.f);
    float inv = 1.f / sqrtf(var + 1e-5f);
    float ln = d * inv * g[f] + bt[f];
    float p0 = ln * lw[f * 2 + 0];
    float p1 = ln * lw[f * 2 + 1];
    #pragma unroll
    for (int mask = 1; mask < 32; mask <<= 1) {
        p0 += __shfl_xor(p0, mask, 64);
        p1 += __shfl_xor(p1, mask, 64);
    }
    if (f == 0) {
        out[(size_t)node * 2 + 0] = p0 + lb[0];
        out[(size_t)node * 2 + 1] = p1 + lb[1];
    }
}

extern "C" void kernel_launch(void* const* d_in, const int* in_sizes, int n_in,
                              void* d_out, int out_size, void* d_ws, size_t ws_size,
                              hipStream_t stream) {
    const float* x_addr = (const float*)d_in[0];
    const float* x_tx   = (const float*)d_in[1];
    const int* ei_in    = (const int*)d_in[2];
    const int* ei_out   = (const int*)d_in[3];
    const int* ei_sp    = (const int*)d_in[4];
    const float* enc_w_addr = (const float*)d_in[5];
    const float* enc_b_addr = (const float*)d_in[6];
    const float* enc_w_tx   = (const float*)d_in[7];
    const float* enc_b_tx   = (const float*)d_in[8];
    const float* ln_ag = (const float*)d_in[9];
    const float* ln_ab = (const float*)d_in[10];
    const float* ln_tg = (const float*)d_in[11];
    const float* ln_tb = (const float*)d_in[12];
    const float* pw_a = (const float*)d_in[13];
    const float* pb_a = (const float*)d_in[14];
    const float* pw_t = (const float*)d_in[15];
    const float* pb_t = (const float*)d_in[16];
    const float* att_src = (const float*)d_in[17];
    const float* att_dst = (const float*)d_in[18];
    const float* klw = (const float*)d_in[19];
    const float* klb = (const float*)d_in[20];
    const float* qv  = (const float*)d_in[21];
    const float* lin_w = (const float*)d_in[22];
    const float* lin_b = (const float*)d_in[23];
    float* out = (float*)d_out;

    const int NA = in_sizes[0] / 53;
    const int NT = in_sizes[1] / 6;
    const int E_IN = in_sizes[2] / 2;
    const int E_OUT = in_sizes[3] / 2;
    const int E_SP = in_sizes[4] / 2;
    const int E_TOT = E_IN + E_OUT + E_SP;
    const int NCAT = NT + NA + NT;
    const int NB = (NCAT + (1 << BSHIFT) - 1) >> BSHIFT;   // buckets (<= MAXNB)

    size_t off = 0;
    float* base = (float*)d_ws;
    auto alloc = [&](size_t nfloats) {
        float* p = base + off;
        off += (nfloats + 63) & ~(size_t)63;
        return p;
    };
    float* xa      = alloc((size_t)NA * 32);
    float* xt      = alloc((size_t)NT * 32);
    float* agg_a_f = alloc((size_t)NA * 16);
    float* agg_t0f = alloc((size_t)NT * 16);
    float* agg_t2f = alloc((size_t)NT * 16);
    float* h_t_f   = alloc((size_t)NT * 16);
    float* asrc0a  = alloc((size_t)NA * 4);
    float* adst1a  = alloc((size_t)NA * 4);
    float* asrc1t  = alloc((size_t)NT * 4);
    float* adst0t  = alloc((size_t)NT * 4);
    float* asrc2t  = alloc((size_t)NT * 4);
    float* adst2t  = alloc((size_t)NT * 4);
    int* rowptrAll = (int*)alloc((size_t)NCAT + 64);
    int* colAll    = (int*)alloc((size_t)E_TOT);
    // bcnt + scores contiguous -> single zero launch covers both
    int* bcnt      = (int*)alloc(MAXNB + 64);
    float* scores  = alloc(64);
    int* bstart    = (int*)alloc(MAXNB + 64);
    int* bcur      = (int*)alloc(MAXNB + 64);

    // pairs buffer aliases xa: CSR build fully precedes encproj's write of xa
    int2* pairs = (int2*)xa;

    // optionally un-alias h_a from agg_a if workspace is big enough
    size_t ha_floats = (((size_t)NA * 16) + 63) & ~(size_t)63;
    bool roomy = ((off + ha_floats) * sizeof(float)) <= ws_size;
    float* h_a_f = roomy ? alloc((size_t)NA * 16) : agg_a_f;

    __half* agg_a  = (__half*)agg_a_f;
    __half* agg_t0 = (__half*)agg_t0f;
    __half* agg_t2 = (__half*)agg_t2f;
    __half* h_t    = (__half*)h_t_f;
    __half* h_a    = (__half*)h_a_f;

    dim3 blk(256);
    int nbA8 = (NA + 7) / 8, nbT8 = (NT + 7) / 8;
    int nbE = (E_TOT + 255) / 256;

    // ---- two-level counting-sort CSR build (once; reused by all layers) ----
    zero_int_kernel<<<64, blk, 0, stream>>>(bcnt, (long)(MAXNB + 64 + 64));
    bucket_hist_kernel<<<512, blk, 0, stream>>>(ei_in, ei_out, ei_sp, E_IN, E_OUT, E_SP,
                                                NT, NA, bcnt, NB, E_TOT);
    bucket_scan_kernel<<<1, 1024, 0, stream>>>(bcnt, bstart, bcur, NB, E_TOT);
    pair_scatter_kernel<<<nbE, blk, 0, stream>>>(ei_in, ei_out, ei_sp, E_IN, E_OUT, E_SP,
                                                 NT, NA, bcur, pairs, E_TOT);
    bucket_sort_kernel<<<NB, blk, 0, stream>>>(pairs, bstart, rowptrAll, colAll, NCAT, E_TOT);

    // ---- fused encoder + layer-0 projection ----
    encproj_addr_kernel<<<nbA8, blk, 0, stream>>>(
        x_addr, enc_w_addr, enc_b_addr, pw_a, pb_a,
        att_src + 0 * 32, att_dst + 1 * 32,
        xa, h_a, asrc0a, adst1a, NA);
    encproj_tx_kernel<<<nbT8, blk, 0, stream>>>(
        x_tx, enc_w_tx, enc_b_tx, pw_t, pb_t,
        att_src + 1 * 32, att_dst + 0 * 32, att_src + 2 * 32, att_dst + 2 * 32,
        xt, h_t, asrc1t, adst0t, asrc2t, adst2t, NT);

    auto agg_launch = [&](int mode, int nRows, const float* kw, const float* kb,
                          const float* q, float* sc) {
        int blocks = (nRows + 15) / 16;
        if (blocks > 2048) blocks = 2048;
        agg_all_kernel<<<blocks, blk, 0, stream>>>(
            rowptrAll, colAll, h_a, h_t,
            asrc0a, adst0t, asrc1t, adst1a, asrc2t, adst2t,
            agg_t0, agg_a, agg_t2, kw, kb, q, sc, NT, NA, mode, nRows);
    };

    for (int l = 0; l < NLAYERS; l++) {
        bool last = (l == NLAYERS - 1);
        const float* kw = klw + l * 1024;
        const float* kb = klb + l * 32;
        const float* q  = qv + l * 32;
        float* sc = scores + 2 * l;
        if (!last) {
            if (roomy) {
                agg_launch(0, NCAT, kw, kb, q, sc);
            } else {
                agg_launch(1, 2 * NT, kw, kb, q, sc);  // rel0+rel2 (h_a alias still live)
                agg_launch(2, NA, kw, kb, q, sc);      // rel1 (overwrites h_a region)
            }
            int lp = l + 1;
            combineproj_kernel<<<nbA8 + nbT8, blk, 0, stream>>>(
                agg_a, agg_t0, agg_t2, xa, xt,
                ln_ag, ln_ab, ln_tg, ln_tb,
                sc, 1.0f / (float)NT,
                pw_a + lp * 1024, pb_a + lp * 32, pw_t + lp * 1024, pb_t + lp * 32,
                att_src + (lp * 3 + 0) * 32, att_dst + (lp * 3 + 1) * 32,
                att_src + (lp * 3 + 1) * 32, att_dst + (lp * 3 + 0) * 32,
                att_src + (lp * 3 + 2) * 32, att_dst + (lp * 3 + 2) * 32,
                h_a, h_t,
                asrc0a, adst1a, asrc1t, adst0t, asrc2t, adst2t,
                NA, NT, nbA8, lp == 3 ? 1 : 0);
        } else {
            agg_launch(2, NA, kw, kb, q, sc);          // rel1 only
            combine_final_kernel<<<nbA8, blk, 0, stream>>>(agg_a, xa, ln_ag, ln_ab,
                                                           lin_w, lin_b, out, NA);
        }
    }
}

// Round 7
// 1407.023 us; speedup vs baseline: 1.3517x; 1.3517x over previous
//
#include <hip/hip_runtime.h>
#include <hip/hip_fp16.h>

#define NLAYERS 4

// ---------------- zero fill ----------------
__global__ void zero_int_kernel(int* __restrict__ p, long n) {
    long i = (long)blockIdx.x * 256 + threadIdx.x;
    long stride = (long)gridDim.x * 256;
    for (; i < n; i += stride) p[i] = 0;
}

__device__ __forceinline__ float fast_tanh(float y) {
    y = fminf(fmaxf(y, -15.f), 15.f);
    float t = __expf(2.f * y);
    return (t - 1.f) / (t + 1.f);
}

// ================= CSR build over concatenated dst space (R5 direct form) =================
// [0,NT) rel0 dsts | [NT,NT+NA) rel1 dsts | [NT+NA,NCAT) rel2 dsts
__device__ __forceinline__ int edge_row(const int* ei_in, const int* ei_out, const int* ei_sp,
                                        int E_IN, int E_OUT, int E_SP, int NT, int NA,
                                        int e, int* src) {
    if (e < E_IN) { *src = ei_in[e]; return ei_in[E_IN + e]; }
    if (e < E_IN + E_OUT) { int i = e - E_IN; *src = ei_out[i]; return NT + ei_out[E_OUT + i]; }
    int i = e - E_IN - E_OUT; *src = ei_sp[i]; return NT + NA + ei_sp[E_SP + i];
}

__global__ void hist_kernel(const int* __restrict__ ei_in, const int* __restrict__ ei_out,
                            const int* __restrict__ ei_sp, int E_IN, int E_OUT, int E_SP,
                            int NT, int NA, int* __restrict__ deg, int E_TOT) {
    int e = blockIdx.x * 256 + threadIdx.x;
    if (e >= E_TOT) return;
    int s;
    int row = edge_row(ei_in, ei_out, ei_sp, E_IN, E_OUT, E_SP, NT, NA, e, &s);
    atomicAdd(&deg[row], 1);
}

__global__ void scan1_kernel(const int* __restrict__ deg, int* __restrict__ rowptr,
                             int* __restrict__ bsum, int n) {
    __shared__ int lds[256];
    int tid = threadIdx.x;
    int base = blockIdx.x * 1024;
    int v[4];
    int mysum = 0;
    #pragma unroll
    for (int j = 0; j < 4; j++) {
        int idx = base + tid * 4 + j;
        v[j] = (idx < n) ? deg[idx] : 0;
        mysum += v[j];
    }
    lds[tid] = mysum;
    __syncthreads();
    for (int off = 1; off < 256; off <<= 1) {
        int t = (tid >= off) ? lds[tid - off] : 0;
        __syncthreads();
        lds[tid] += t;
        __syncthreads();
    }
    int excl = lds[tid] - mysum;
    if (tid == 255) bsum[blockIdx.x] = lds[tid];
    int run = excl;
    #pragma unroll
    for (int j = 0; j < 4; j++) {
        int idx = base + tid * 4 + j;
        if (idx < n) rowptr[idx] = run;
        run += v[j];
    }
}

__global__ void scan2_kernel(int* __restrict__ bsum, int nb) {
    __shared__ int lds[1024];
    int tid = threadIdx.x;
    int v = (tid < nb) ? bsum[tid] : 0;
    lds[tid] = v;
    __syncthreads();
    for (int off = 1; off < 1024; off <<= 1) {
        int t = (tid >= off) ? lds[tid - off] : 0;
        __syncthreads();
        lds[tid] += t;
        __syncthreads();
    }
    if (tid < nb) bsum[tid] = lds[tid] - v;
}

__global__ void scan3_kernel(int* __restrict__ rowptr, const int* __restrict__ bsum,
                             int* __restrict__ cursor, int n, int E) {
    int i = blockIdx.x * 256 + threadIdx.x;
    if (i < n) {
        int r = rowptr[i] + bsum[i >> 10];
        rowptr[i] = r;
        cursor[i] = r;
    }
    if (i == 0) rowptr[n] = E;
}

__global__ void scatter_kernel(const int* __restrict__ ei_in, const int* __restrict__ ei_out,
                               const int* __restrict__ ei_sp, int E_IN, int E_OUT, int E_SP,
                               int NT, int NA, int* __restrict__ cursor, int* __restrict__ col,
                               int E_TOT) {
    int e = blockIdx.x * 256 + threadIdx.x;
    if (e >= E_TOT) return;
    int s;
    int row = edge_row(ei_in, ei_out, ei_sp, E_IN, E_OUT, E_SP, NT, NA, e, &s);
    int pos = atomicAdd(&cursor[row], 1);
    col[pos] = s;
}

// ================= fused encoder + layer-0 projection =================
__global__ void encproj_addr_kernel(const float* __restrict__ x,
                                    const float* __restrict__ We, const float* __restrict__ be,
                                    const float* __restrict__ Wp, const float* __restrict__ bp,
                                    const float* __restrict__ a0, const float* __restrict__ a1,
                                    float* __restrict__ xa, __half* __restrict__ h,
                                    float* __restrict__ o0, float* __restrict__ o1, int n) {
    __shared__ float sWe[53 * 32];
    __shared__ float sW[1024];
    __shared__ float sv[3][32];
    __shared__ float sbp[32];
    __shared__ float sx[8][56];
    __shared__ float sh[8][33];
    int tid = threadIdx.x;
    for (int i = tid; i < 53 * 32; i += 256) sWe[i] = We[i];
    for (int i = tid; i < 1024; i += 256) sW[i] = Wp[i];
    if (tid < 32) { sv[0][tid] = be[tid]; sv[1][tid] = a0[tid]; sv[2][tid] = a1[tid]; sbp[tid] = bp[tid]; }
    int local = tid >> 5, f = tid & 31;
    int node = blockIdx.x * 8 + local;
    if (node < n) {
        for (int k = f; k < 53; k += 32) sx[local][k] = x[(size_t)node * 53 + k];
    }
    __syncthreads();
    float xe = 0.f;
    if (node < n) {
        float acc = sv[0][f];
        for (int k = 0; k < 53; k++) acc += sx[local][k] * sWe[k * 32 + f];
        xe = fmaxf(acc, 0.f);
        xa[(size_t)node * 32 + f] = xe;
    }
    sh[local][f] = xe;
    __syncthreads();
    float accp = 0.f;
    if (node < n) {
        accp = sbp[f];
        #pragma unroll
        for (int k = 0; k < 32; k++) accp += sh[local][k] * sW[k * 32 + f];
        h[(size_t)node * 32 + f] = __float2half(accp);
    }
    __syncthreads();
    sh[local][f] = accp;
    __syncthreads();
    if (node < n && f < 8) {
        int vec = f >> 2, head = f & 3;
        const float* av = sv[1 + vec];
        float dsum = 0.f;
        #pragma unroll
        for (int dd = 0; dd < 8; dd++) dsum += sh[local][head * 8 + dd] * av[head * 8 + dd];
        (vec == 0 ? o0 : o1)[(size_t)node * 4 + head] = dsum;
    }
}

__global__ void encproj_tx_kernel(const float* __restrict__ x,
                                  const float* __restrict__ We, const float* __restrict__ be,
                                  const float* __restrict__ Wp, const float* __restrict__ bp,
                                  const float* __restrict__ a0, const float* __restrict__ a1,
                                  const float* __restrict__ a2, const float* __restrict__ a3,
                                  float* __restrict__ xt, __half* __restrict__ h,
                                  float* __restrict__ o0, float* __restrict__ o1,
                                  float* __restrict__ o2, float* __restrict__ o3, int n) {
    __shared__ float sWe[6 * 32];
    __shared__ float sW[1024];
    __shared__ float sv[5][32];
    __shared__ float sbp[32];
    __shared__ float sx[8][8];
    __shared__ float sh[8][33];
    int tid = threadIdx.x;
    for (int i = tid; i < 6 * 32; i += 256) sWe[i] = We[i];
    for (int i = tid; i < 1024; i += 256) sW[i] = Wp[i];
    if (tid < 32) {
        sv[0][tid] = be[tid]; sv[1][tid] = a0[tid]; sv[2][tid] = a1[tid];
        sv[3][tid] = a2[tid]; sv[4][tid] = a3[tid]; sbp[tid] = bp[tid];
    }
    int local = tid >> 5, f = tid & 31;
    int node = blockIdx.x * 8 + local;
    if (node < n && f < 6) sx[local][f] = x[(size_t)node * 6 + f];
    __syncthreads();
    float xe = 0.f;
    if (node < n) {
        float acc = sv[0][f];
        #pragma unroll
        for (int k = 0; k < 6; k++) acc += sx[local][k] * sWe[k * 32 + f];
        xe = fmaxf(acc, 0.f);
        xt[(size_t)node * 32 + f] = xe;
    }
    sh[local][f] = xe;
    __syncthreads();
    float accp = 0.f;
    if (node < n) {
        accp = sbp[f];
        #pragma unroll
        for (int k = 0; k < 32; k++) accp += sh[local][k] * sW[k * 32 + f];
        h[(size_t)node * 32 + f] = __float2half(accp);
    }
    __syncthreads();
    sh[local][f] = accp;
    __syncthreads();
    if (node < n && f < 16) {
        int vec = f >> 2, head = f & 3;
        const float* av = sv[1 + vec];
        float dsum = 0.f;
        #pragma unroll
        for (int dd = 0; dd < 8; dd++) dsum += sh[local][head * 8 + dd] * av[head * 8 + dd];
        float* op = vec == 0 ? o0 : vec == 1 ? o1 : vec == 2 ? o2 : o3;
        op[(size_t)node * 4 + head] = dsum;
    }
}

// ================= merged CSR aggregation (all rels) + fused semantic score =================
// 16 lanes/dst; edge loop unrolled x2 for memory-level parallelism.
__global__ void agg_all_kernel(
    const int* __restrict__ rowptr, const int* __restrict__ col,
    const __half* __restrict__ h_a, const __half* __restrict__ h_t,
    const float* __restrict__ asrc0, const float* __restrict__ adst0,
    const float* __restrict__ asrc1, const float* __restrict__ adst1,
    const float* __restrict__ asrc2, const float* __restrict__ adst2,
    __half* __restrict__ agg_t0, __half* __restrict__ agg_a, __half* __restrict__ agg_t2,
    const float* __restrict__ kw, const float* __restrict__ kb, const float* __restrict__ q,
    float* __restrict__ scoreOut, int NT, int NA, int mode, int nRows) {
    __shared__ float sW[1024];
    __shared__ float sb[32];
    __shared__ float sq[32];
    __shared__ float sScore[2];
    int tid = threadIdx.x;
    bool doScore = (mode != 2);
    if (doScore) {
        for (int i = tid; i < 1024; i += 256) sW[i] = kw[i];
        if (tid < 32) { sb[tid] = kb[tid]; sq[tid] = q[tid]; }
        if (tid < 2) sScore[tid] = 0.f;
        __syncthreads();
    }
    int lane = tid & 15;
    int head = lane >> 2, f0 = lane * 2;
    long stride = (long)gridDim.x * 16;
    for (long gi = (long)blockIdx.x * 16 + (tid >> 4); gi < (long)nRows; gi += stride) {
        int row;
        if (mode == 0) row = (int)gi;
        else if (mode == 1) row = (gi < NT) ? (int)gi : (int)(gi + NA);
        else row = NT + (int)gi;
        int rel, dst;
        const __half* h; const float* asrc; const float* adp; __half* agg;
        if (row < NT)           { rel = 0; dst = row;           h = h_a; asrc = asrc0; adp = adst0; agg = agg_t0; }
        else if (row < NT + NA) { rel = 1; dst = row - NT;      h = h_t; asrc = asrc1; adp = adst1; agg = agg_a; }
        else                    { rel = 2; dst = row - NT - NA; h = h_t; asrc = asrc2; adp = adst2; agg = agg_t2; }
        float ad = adp[(size_t)dst * 4 + head];
        int e0 = rowptr[row], e1 = rowptr[row + 1];
        float accx = 0.f, accy = 0.f, den = 0.f;
        int e = e0;
        for (; e + 2 <= e1; e += 2) {
            int s0 = col[e], s1 = col[e + 1];
            float t0 = asrc[(size_t)s0 * 4 + head] + ad;
            float t1 = asrc[(size_t)s1 * 4 + head] + ad;
            __half2 hv0 = *(const __half2*)(h + (size_t)s0 * 32 + f0);
            __half2 hv1 = *(const __half2*)(h + (size_t)s1 * 32 + f0);
            t0 = t0 > 0.f ? t0 : 0.2f * t0;
            t1 = t1 > 0.f ? t1 : 0.2f * t1;
            float ex0 = __expf(t0), ex1 = __expf(t1);
            den += ex0 + ex1;
            float2 hf0 = __half22float2(hv0), hf1 = __half22float2(hv1);
            accx += ex0 * hf0.x + ex1 * hf1.x;
            accy += ex0 * hf0.y + ex1 * hf1.y;
        }
        if (e < e1) {
            int s = col[e];
            float t = asrc[(size_t)s * 4 + head] + ad;
            t = t > 0.f ? t : 0.2f * t;
            float ex = __expf(t);
            den += ex;
            float2 hf = __half22float2(*(const __half2*)(h + (size_t)s * 32 + f0));
            accx += ex * hf.x; accy += ex * hf.y;
        }
        float r = 1.f / (den + 1e-16f);
        float vx = accx * r, vy = accy * r;
        __half2 o; o.x = __float2half(vx); o.y = __float2half(vy);
        *(__half2*)(agg + (size_t)dst * 32 + f0) = o;
        if (doScore && rel != 1) {
            float r0 = fmaxf(vx, 0.f), r1 = fmaxf(vy, 0.f);
            float y0 = sb[f0], y1 = sb[f0 + 1];
            #pragma unroll
            for (int k = 0; k < 16; k++) {
                float rx = __shfl(r0, k, 16);
                float ry = __shfl(r1, k, 16);
                y0 += rx * sW[(2 * k) * 32 + f0]     + ry * sW[(2 * k + 1) * 32 + f0];
                y1 += rx * sW[(2 * k) * 32 + f0 + 1] + ry * sW[(2 * k + 1) * 32 + f0 + 1];
            }
            float sacc = sq[f0] * fast_tanh(y0) + sq[f0 + 1] * fast_tanh(y1);
            #pragma unroll
            for (int m = 1; m < 16; m <<= 1) sacc += __shfl_xor(sacc, m, 16);
            if (lane == 0) atomicAdd(&sScore[rel == 2 ? 1 : 0], sacc);
        }
    }
    if (doScore) {
        __syncthreads();
        if (tid < 2) unsafeAtomicAdd(scoreOut + tid, sScore[tid]);
    }
}

// ================= fused combine(layer l) + projection(layer l+1), 16 nodes/block =================
__global__ void combineproj_kernel(
    const __half* __restrict__ agg_a, const __half* __restrict__ agg_t0, const __half* __restrict__ agg_t2,
    float* __restrict__ xa, float* __restrict__ xt,
    const float* __restrict__ ln_ag, const float* __restrict__ ln_ab,
    const float* __restrict__ ln_tg, const float* __restrict__ ln_tb,
    const float* __restrict__ scores, float invNT,
    const float* __restrict__ Wa, const float* __restrict__ Ba,
    const float* __restrict__ Wt, const float* __restrict__ Bt,
    const float* __restrict__ as0, const float* __restrict__ ad1,
    const float* __restrict__ as1, const float* __restrict__ ad0,
    const float* __restrict__ as2, const float* __restrict__ ad2,
    __half* __restrict__ h_a, __half* __restrict__ h_t,
    float* __restrict__ o_as0, float* __restrict__ o_ad1,
    float* __restrict__ o_as1, float* __restrict__ o_ad0,
    float* __restrict__ o_as2, float* __restrict__ o_ad2,
    int NA_, int NT_, int nbA16, int lastProj) {
    __shared__ float sW[1024];
    __shared__ float sv[5][32];
    __shared__ float sbp[32];
    __shared__ float sh[16][33];
    int tid = threadIdx.x;
    bool isA = blockIdx.x < nbA16;
    const float* W = isA ? Wa : Wt;
    for (int i = tid; i < 1024; i += 256) sW[i] = W[i];
    if (tid < 32) {
        sbp[tid] = (isA ? Ba : Bt)[tid];
        sv[1][tid] = (isA ? as0 : as1)[tid];
        sv[2][tid] = (isA ? ad1 : ad0)[tid];
        if (!isA) { sv[3][tid] = as2[tid]; sv[4][tid] = ad2[tid]; }
    }
    int local = tid >> 5, f = tid & 31;
    int n = isA ? NA_ : NT_;
    int base = (isA ? blockIdx.x : blockIdx.x - nbA16) * 16;
    int node0 = base + local, node1 = base + local + 8;
    float wsem0 = 0.f, wsem2 = 0.f;
    if (!isA) {
        float s0 = scores[0] * invNT, s2 = scores[1] * invNT;
        float mx = fmaxf(s0, s2);
        float e0 = __expf(s0 - mx), e2 = __expf(s2 - mx);
        float inv_s = 1.f / (e0 + e2);
        wsem0 = e0 * inv_s; wsem2 = e2 * inv_s;
    }
    const float* lng = isA ? ln_ag : ln_tg;
    const float* lnb = isA ? ln_ab : ln_tb;
    float gln = lng[f], bln = lnb[f];
    float ln0 = 0.f, ln1 = 0.f;
    // --- node0 combine + LN ---
    if (node0 < n) {
        float v;
        if (isA) {
            v = fmaxf(__half2float(agg_a[(size_t)node0 * 32 + f]), 0.f) + xa[(size_t)node0 * 32 + f];
        } else {
            float a0 = fmaxf(__half2float(agg_t0[(size_t)node0 * 32 + f]), 0.f);
            float a2 = fmaxf(__half2float(agg_t2[(size_t)node0 * 32 + f]), 0.f);
            v = fmaxf(wsem0 * a0 + wsem2 * a2, 0.f) + xt[(size_t)node0 * 32 + f];
        }
        float m = v;
        #pragma unroll
        for (int mask = 1; mask < 32; mask <<= 1) m += __shfl_xor(m, mask, 64);
        m *= (1.f / 32.f);
        float d = v - m;
        float var = d * d;
        #pragma unroll
        for (int mask = 1; mask < 32; mask <<= 1) var += __shfl_xor(var, mask, 64);
        var *= (1.f / 32.f);
        ln0 = d * (1.f / sqrtf(var + 1e-5f)) * gln + bln;
        if (isA) xa[(size_t)node0 * 32 + f] = ln0;
        else if (!lastProj) xt[(size_t)node0 * 32 + f] = ln0;
    }
    // --- node1 combine + LN ---
    if (node1 < n) {
        float v;
        if (isA) {
            v = fmaxf(__half2float(agg_a[(size_t)node1 * 32 + f]), 0.f) + xa[(size_t)node1 * 32 + f];
        } else {
            float a0 = fmaxf(__half2float(agg_t0[(size_t)node1 * 32 + f]), 0.f);
            float a2 = fmaxf(__half2float(agg_t2[(size_t)node1 * 32 + f]), 0.f);
            v = fmaxf(wsem0 * a0 + wsem2 * a2, 0.f) + xt[(size_t)node1 * 32 + f];
        }
        float m = v;
        #pragma unroll
        for (int mask = 1; mask < 32; mask <<= 1) m += __shfl_xor(m, mask, 64);
        m *= (1.f / 32.f);
        float d = v - m;
        float var = d * d;
        #pragma unroll
        for (int mask = 1; mask < 32; mask <<= 1) var += __shfl_xor(var, mask, 64);
        var *= (1.f / 32.f);
        ln1 = d * (1.f / sqrtf(var + 1e-5f)) * gln + bln;
        if (isA) xa[(size_t)node1 * 32 + f] = ln1;
        else if (!lastProj) xt[(size_t)node1 * 32 + f] = ln1;
    }
    sh[local][f] = ln0;
    sh[local + 8][f] = ln1;
    __syncthreads();
    // --- projection: 2 nodes per thread, shared sW read ---
    float acc0 = sbp[f], acc1 = sbp[f];
    #pragma unroll
    for (int k = 0; k < 32; k++) {
        float w = sW[k * 32 + f];
        acc0 += sh[local][k] * w;
        acc1 += sh[local + 8][k] * w;
    }
    bool writeH = (!isA || !lastProj);
    __half* hptr = isA ? h_a : h_t;
    if (writeH) {
        if (node0 < n) hptr[(size_t)node0 * 32 + f] = __float2half(acc0);
        if (node1 < n) hptr[(size_t)node1 * 32 + f] = __float2half(acc1);
    }
    __syncthreads();
    sh[local][f] = acc0;
    sh[local + 8][f] = acc1;
    __syncthreads();
    int nvec = isA ? 8 : 16;
    if (f < nvec) {
        int vec = f >> 2, head = f & 3;
        bool need = !lastProj || (isA ? (vec == 1) : (vec == 0));
        if (need) {
            const float* av = sv[1 + vec];
            float d0 = 0.f, d1 = 0.f;
            #pragma unroll
            for (int dd = 0; dd < 8; dd++) {
                float a = av[head * 8 + dd];
                d0 += sh[local][head * 8 + dd] * a;
                d1 += sh[local + 8][head * 8 + dd] * a;
            }
            float* op;
            if (isA) op = vec == 0 ? o_as0 : o_ad1;
            else op = vec == 0 ? o_as1 : vec == 1 ? o_ad0 : vec == 2 ? o_as2 : o_ad2;
            if (node0 < n) op[(size_t)node0 * 4 + head] = d0;
            if (node1 < n) op[(size_t)node1 * 4 + head] = d1;
        }
    }
}

// ================= layer-3 combine_addr + output head =================
__global__ void combine_final_kernel(const __half* __restrict__ agg_a, const float* __restrict__ xa,
                                     const float* __restrict__ g, const float* __restrict__ bt,
                                     const float* __restrict__ lw, const float* __restrict__ lb,
                                     float* __restrict__ out, int n) {
    int tid = threadIdx.x;
    int local = tid >> 5, f = tid & 31;
    int node = blockIdx.x * 8 + local;
    if (node >= n) return;
    float a = __half2float(agg_a[(size_t)node * 32 + f]);
    float v = fmaxf(a, 0.f) + xa[(size_t)node * 32 + f];
    float m = v;
    #pragma unroll
    for (int mask = 1; mask < 32; mask <<= 1) m += __shfl_xor(m, mask, 64);
    m *= (1.f / 32.f);
    float d = v - m;
    float var = d * d;
    #pragma unroll
    for (int mask = 1; mask < 32; mask <<= 1) var += __shfl_xor(var, mask, 64);
    var *= (1.f / 32.f);
    float inv = 1.f / sqrtf(var + 1e-5f);
    float ln = d * inv * g[f] + bt[f];
    float p0 = ln * lw[f * 2 + 0];
    float p1 = ln * lw[f * 2 + 1];
    #pragma unroll
    for (int mask = 1; mask < 32; mask <<= 1) {
        p0 += __shfl_xor(p0, mask, 64);
        p1 += __shfl_xor(p1, mask, 64);
    }
    if (f == 0) {
        out[(size_t)node * 2 + 0] = p0 + lb[0];
        out[(size_t)node * 2 + 1] = p1 + lb[1];
    }
}

extern "C" void kernel_launch(void* const* d_in, const int* in_sizes, int n_in,
                              void* d_out, int out_size, void* d_ws, size_t ws_size,
                              hipStream_t stream) {
    const float* x_addr = (const float*)d_in[0];
    const float* x_tx   = (const float*)d_in[1];
    const int* ei_in    = (const int*)d_in[2];
    const int* ei_out   = (const int*)d_in[3];
    const int* ei_sp    = (const int*)d_in[4];
    const float* enc_w_addr = (const float*)d_in[5];
    const float* enc_b_addr = (const float*)d_in[6];
    const float* enc_w_tx   = (const float*)d_in[7];
    const float* enc_b_tx   = (const float*)d_in[8];
    const float* ln_ag = (const float*)d_in[9];
    const float* ln_ab = (const float*)d_in[10];
    const float* ln_tg = (const float*)d_in[11];
    const float* ln_tb = (const float*)d_in[12];
    const float* pw_a = (const float*)d_in[13];
    const float* pb_a = (const float*)d_in[14];
    const float* pw_t = (const float*)d_in[15];
    const float* pb_t = (const float*)d_in[16];
    const float* att_src = (const float*)d_in[17];
    const float* att_dst = (const float*)d_in[18];
    const float* klw = (const float*)d_in[19];
    const float* klb = (const float*)d_in[20];
    const float* qv  = (const float*)d_in[21];
    const float* lin_w = (const float*)d_in[22];
    const float* lin_b = (const float*)d_in[23];
    float* out = (float*)d_out;

    const int NA = in_sizes[0] / 53;
    const int NT = in_sizes[1] / 6;
    const int E_IN = in_sizes[2] / 2;
    const int E_OUT = in_sizes[3] / 2;
    const int E_SP = in_sizes[4] / 2;
    const int E_TOT = E_IN + E_OUT + E_SP;
    const int NCAT = NT + NA + NT;

    size_t off = 0;
    float* base = (float*)d_ws;
    auto alloc = [&](size_t nfloats) {
        float* p = base + off;
        off += (nfloats + 63) & ~(size_t)63;
        return p;
    };
    float* xa      = alloc((size_t)NA * 32);
    float* xt      = alloc((size_t)NT * 32);
    float* agg_a_f = alloc((size_t)NA * 16);
    float* agg_t0f = alloc((size_t)NT * 16);
    float* agg_t2f = alloc((size_t)NT * 16);
    float* h_t_f   = alloc((size_t)NT * 16);
    float* asrc0a  = alloc((size_t)NA * 4);
    float* adst1a  = alloc((size_t)NA * 4);
    float* asrc1t  = alloc((size_t)NT * 4);
    float* adst0t  = alloc((size_t)NT * 4);
    float* asrc2t  = alloc((size_t)NT * 4);
    float* adst2t  = alloc((size_t)NT * 4);
    int* rowptrAll = (int*)alloc((size_t)NCAT + 64);
    int* colAll    = (int*)alloc((size_t)E_TOT);
    // tmp + bsum + scores contiguous -> one zero launch covers all
    size_t tmp_span = (((size_t)NCAT + 63) & ~(size_t)63) + 1088 + 64;
    int* tmp       = (int*)alloc((size_t)NCAT);   // deg, then cursor
    int* bsum      = (int*)alloc(1088);
    float* scores  = alloc(64);

    // optionally un-alias h_a from agg_a if workspace is big enough
    size_t ha_floats = (((size_t)NA * 16) + 63) & ~(size_t)63;
    bool roomy = ((off + ha_floats) * sizeof(float)) <= ws_size;
    float* h_a_f = roomy ? alloc((size_t)NA * 16) : agg_a_f;

    __half* agg_a  = (__half*)agg_a_f;
    __half* agg_t0 = (__half*)agg_t0f;
    __half* agg_t2 = (__half*)agg_t2f;
    __half* h_t    = (__half*)h_t_f;
    __half* h_a    = (__half*)h_a_f;

    dim3 blk(256);
    int nbA8 = (NA + 7) / 8, nbT8 = (NT + 7) / 8;
    int nbA16 = (NA + 15) / 16, nbT16 = (NT + 15) / 16;
    int nbE = (E_TOT + 255) / 256;
    int nbScan = (NCAT + 1023) / 1024;

    // ---- CSR build (R5 direct form; once, reused by all layers) ----
    zero_int_kernel<<<2048, blk, 0, stream>>>(tmp, (long)tmp_span);
    hist_kernel<<<nbE, blk, 0, stream>>>(ei_in, ei_out, ei_sp, E_IN, E_OUT, E_SP, NT, NA, tmp, E_TOT);
    scan1_kernel<<<nbScan, blk, 0, stream>>>(tmp, rowptrAll, bsum, NCAT);
    scan2_kernel<<<1, 1024, 0, stream>>>(bsum, nbScan);
    scan3_kernel<<<(NCAT + 255) / 256, blk, 0, stream>>>(rowptrAll, bsum, tmp, NCAT, E_TOT);
    scatter_kernel<<<nbE, blk, 0, stream>>>(ei_in, ei_out, ei_sp, E_IN, E_OUT, E_SP, NT, NA, tmp, colAll, E_TOT);

    // ---- fused encoder + layer-0 projection ----
    encproj_addr_kernel<<<nbA8, blk, 0, stream>>>(
        x_addr, enc_w_addr, enc_b_addr, pw_a, pb_a,
        att_src + 0 * 32, att_dst + 1 * 32,
        xa, h_a, asrc0a, adst1a, NA);
    encproj_tx_kernel<<<nbT8, blk, 0, stream>>>(
        x_tx, enc_w_tx, enc_b_tx, pw_t, pb_t,
        att_src + 1 * 32, att_dst + 0 * 32, att_src + 2 * 32, att_dst + 2 * 32,
        xt, h_t, asrc1t, adst0t, asrc2t, adst2t, NT);

    auto agg_launch = [&](int mode, int nRows, const float* kw, const float* kb,
                          const float* q, float* sc) {
        int blocks = (nRows + 15) / 16;
        if (blocks > 2048) blocks = 2048;
        agg_all_kernel<<<blocks, blk, 0, stream>>>(
            rowptrAll, colAll, h_a, h_t,
            asrc0a, adst0t, asrc1t, adst1a, asrc2t, adst2t,
            agg_t0, agg_a, agg_t2, kw, kb, q, sc, NT, NA, mode, nRows);
    };

    for (int l = 0; l < NLAYERS; l++) {
        bool last = (l == NLAYERS - 1);
        const float* kw = klw + l * 1024;
        const float* kb = klb + l * 32;
        const float* q  = qv + l * 32;
        float* sc = scores + 2 * l;
        if (!last) {
            if (roomy) {
                agg_launch(0, NCAT, kw, kb, q, sc);
            } else {
                agg_launch(1, 2 * NT, kw, kb, q, sc);  // rel0+rel2 (h_a alias still live)
                agg_launch(2, NA, kw, kb, q, sc);      // rel1 (overwrites h_a region)
            }
            int lp = l + 1;
            combineproj_kernel<<<nbA16 + nbT16, blk, 0, stream>>>(
                agg_a, agg_t0, agg_t2, xa, xt,
                ln_ag, ln_ab, ln_tg, ln_tb,
                sc, 1.0f / (float)NT,
                pw_a + lp * 1024, pb_a + lp * 32, pw_t + lp * 1024, pb_t + lp * 32,
                att_src + (lp * 3 + 0) * 32, att_dst + (lp * 3 + 1) * 32,
                att_src + (lp * 3 + 1) * 32, att_dst + (lp * 3 + 0) * 32,
                att_src + (lp * 3 + 2) * 32, att_dst + (lp * 3 + 2) * 32,
                h_a, h_t,
                asrc0a, adst1a, asrc1t, adst0t, asrc2t, adst2t,
                NA, NT, nbA16, lp == 3 ? 1 : 0);
        } else {
            agg_launch(2, NA, kw, kb, q, sc);          // rel1 only
            combine_final_kernel<<<nbA8, blk, 0, stream>>>(agg_a, xa, ln_ag, ln_ab,
                                                           lin_w, lin_b, out, NA);
        }
    }
}

// Round 8
// 1373.370 us; speedup vs baseline: 1.3849x; 1.0245x over previous
//
#include <hip/hip_runtime.h>
#include <hip/hip_fp16.h>

#define NLAYERS 4

// ---------------- zero fill ----------------
__global__ void zero_int_kernel(int* __restrict__ p, long n) {
    long i = (long)blockIdx.x * 256 + threadIdx.x;
    long stride = (long)gridDim.x * 256;
    for (; i < n; i += stride) p[i] = 0;
}

__device__ __forceinline__ float fast_tanh(float y) {
    y = fminf(fmaxf(y, -15.f), 15.f);
    float t = __expf(2.f * y);
    return (t - 1.f) / (t + 1.f);
}

// ================= CSR build over concatenated dst space =================
// [0,NT) rel0 dsts | [NT,NT+NA) rel1 dsts | [NT+NA,NCAT) rel2 dsts
__device__ __forceinline__ int edge_row(const int* ei_in, const int* ei_out, const int* ei_sp,
                                        int E_IN, int E_OUT, int E_SP, int NT, int NA,
                                        int e, int* src) {
    if (e < E_IN) { *src = ei_in[e]; return ei_in[E_IN + e]; }
    if (e < E_IN + E_OUT) { int i = e - E_IN; *src = ei_out[i]; return NT + ei_out[E_OUT + i]; }
    int i = e - E_IN - E_OUT; *src = ei_sp[i]; return NT + NA + ei_sp[E_SP + i];
}

__global__ void hist_kernel(const int* __restrict__ ei_in, const int* __restrict__ ei_out,
                            const int* __restrict__ ei_sp, int E_IN, int E_OUT, int E_SP,
                            int NT, int NA, int* __restrict__ deg, int E_TOT) {
    int e = blockIdx.x * 256 + threadIdx.x;
    if (e >= E_TOT) return;
    int s;
    int row = edge_row(ei_in, ei_out, ei_sp, E_IN, E_OUT, E_SP, NT, NA, e, &s);
    atomicAdd(&deg[row], 1);
}

__global__ void scan1_kernel(const int* __restrict__ deg, int* __restrict__ rowptr,
                             int* __restrict__ bsum, int n) {
    __shared__ int lds[256];
    int tid = threadIdx.x;
    int base = blockIdx.x * 1024;
    int v[4];
    int mysum = 0;
    #pragma unroll
    for (int j = 0; j < 4; j++) {
        int idx = base + tid * 4 + j;
        v[j] = (idx < n) ? deg[idx] : 0;
        mysum += v[j];
    }
    lds[tid] = mysum;
    __syncthreads();
    for (int off = 1; off < 256; off <<= 1) {
        int t = (tid >= off) ? lds[tid - off] : 0;
        __syncthreads();
        lds[tid] += t;
        __syncthreads();
    }
    int excl = lds[tid] - mysum;
    if (tid == 255) bsum[blockIdx.x] = lds[tid];
    int run = excl;
    #pragma unroll
    for (int j = 0; j < 4; j++) {
        int idx = base + tid * 4 + j;
        if (idx < n) rowptr[idx] = run;
        run += v[j];
    }
}

__global__ void scan2_kernel(int* __restrict__ bsum, int nb) {
    __shared__ int lds[1024];
    int tid = threadIdx.x;
    int v = (tid < nb) ? bsum[tid] : 0;
    lds[tid] = v;
    __syncthreads();
    for (int off = 1; off < 1024; off <<= 1) {
        int t = (tid >= off) ? lds[tid - off] : 0;
        __syncthreads();
        lds[tid] += t;
        __syncthreads();
    }
    if (tid < nb) bsum[tid] = lds[tid] - v;
}

__global__ void scan3_kernel(int* __restrict__ rowptr, const int* __restrict__ bsum,
                             int* __restrict__ cursor, int n, int E) {
    int i = blockIdx.x * 256 + threadIdx.x;
    if (i < n) {
        int r = rowptr[i] + bsum[i >> 10];
        rowptr[i] = r;
        cursor[i] = r;
    }
    if (i == 0) rowptr[n] = E;
}

__global__ void scatter_kernel(const int* __restrict__ ei_in, const int* __restrict__ ei_out,
                               const int* __restrict__ ei_sp, int E_IN, int E_OUT, int E_SP,
                               int NT, int NA, int* __restrict__ cursor, int* __restrict__ col,
                               int E_TOT) {
    int e = blockIdx.x * 256 + threadIdx.x;
    if (e >= E_TOT) return;
    int s;
    int row = edge_row(ei_in, ei_out, ei_sp, E_IN, E_OUT, E_SP, NT, NA, e, &s);
    int pos = atomicAdd(&cursor[row], 1);
    col[pos] = s;
}

// ================= fused encoder + layer-0 projection =================
__global__ void encproj_addr_kernel(const float* __restrict__ x,
                                    const float* __restrict__ We, const float* __restrict__ be,
                                    const float* __restrict__ Wp, const float* __restrict__ bp,
                                    const float* __restrict__ a0, const float* __restrict__ a1,
                                    float* __restrict__ xa, __half* __restrict__ h,
                                    __half* __restrict__ o0, float* __restrict__ o1, int n) {
    __shared__ float sWe[53 * 32];
    __shared__ float sW[1024];
    __shared__ float sv[3][32];
    __shared__ float sbp[32];
    __shared__ float sx[8][56];
    __shared__ float sh[8][33];
    int tid = threadIdx.x;
    for (int i = tid; i < 53 * 32; i += 256) sWe[i] = We[i];
    for (int i = tid; i < 1024; i += 256) sW[i] = Wp[i];
    if (tid < 32) { sv[0][tid] = be[tid]; sv[1][tid] = a0[tid]; sv[2][tid] = a1[tid]; sbp[tid] = bp[tid]; }
    int local = tid >> 5, f = tid & 31;
    int node = blockIdx.x * 8 + local;
    if (node < n) {
        for (int k = f; k < 53; k += 32) sx[local][k] = x[(size_t)node * 53 + k];
    }
    __syncthreads();
    float xe = 0.f;
    if (node < n) {
        float acc = sv[0][f];
        for (int k = 0; k < 53; k++) acc += sx[local][k] * sWe[k * 32 + f];
        xe = fmaxf(acc, 0.f);
        xa[(size_t)node * 32 + f] = xe;
    }
    sh[local][f] = xe;
    __syncthreads();
    float accp = 0.f;
    if (node < n) {
        accp = sbp[f];
        #pragma unroll
        for (int k = 0; k < 32; k++) accp += sh[local][k] * sW[k * 32 + f];
        h[(size_t)node * 32 + f] = __float2half(accp);
    }
    __syncthreads();
    sh[local][f] = accp;
    __syncthreads();
    if (node < n && f < 8) {
        int vec = f >> 2, head = f & 3;
        const float* av = sv[1 + vec];
        float dsum = 0.f;
        #pragma unroll
        for (int dd = 0; dd < 8; dd++) dsum += sh[local][head * 8 + dd] * av[head * 8 + dd];
        if (vec == 0) o0[(size_t)node * 4 + head] = __float2half(dsum);
        else o1[(size_t)node * 4 + head] = dsum;
    }
}

__global__ void encproj_tx_kernel(const float* __restrict__ x,
                                  const float* __restrict__ We, const float* __restrict__ be,
                                  const float* __restrict__ Wp, const float* __restrict__ bp,
                                  const float* __restrict__ a0, const float* __restrict__ a1,
                                  const float* __restrict__ a2, const float* __restrict__ a3,
                                  float* __restrict__ xt, __half* __restrict__ h,
                                  __half* __restrict__ o0, float* __restrict__ o1,
                                  __half* __restrict__ o2, float* __restrict__ o3, int n) {
    __shared__ float sWe[6 * 32];
    __shared__ float sW[1024];
    __shared__ float sv[5][32];
    __shared__ float sbp[32];
    __shared__ float sx[8][8];
    __shared__ float sh[8][33];
    int tid = threadIdx.x;
    for (int i = tid; i < 6 * 32; i += 256) sWe[i] = We[i];
    for (int i = tid; i < 1024; i += 256) sW[i] = Wp[i];
    if (tid < 32) {
        sv[0][tid] = be[tid]; sv[1][tid] = a0[tid]; sv[2][tid] = a1[tid];
        sv[3][tid] = a2[tid]; sv[4][tid] = a3[tid]; sbp[tid] = bp[tid];
    }
    int local = tid >> 5, f = tid & 31;
    int node = blockIdx.x * 8 + local;
    if (node < n && f < 6) sx[local][f] = x[(size_t)node * 6 + f];
    __syncthreads();
    float xe = 0.f;
    if (node < n) {
        float acc = sv[0][f];
        #pragma unroll
        for (int k = 0; k < 6; k++) acc += sx[local][k] * sWe[k * 32 + f];
        xe = fmaxf(acc, 0.f);
        xt[(size_t)node * 32 + f] = xe;
    }
    sh[local][f] = xe;
    __syncthreads();
    float accp = 0.f;
    if (node < n) {
        accp = sbp[f];
        #pragma unroll
        for (int k = 0; k < 32; k++) accp += sh[local][k] * sW[k * 32 + f];
        h[(size_t)node * 32 + f] = __float2half(accp);
    }
    __syncthreads();
    sh[local][f] = accp;
    __syncthreads();
    if (node < n && f < 16) {
        int vec = f >> 2, head = f & 3;
        const float* av = sv[1 + vec];
        float dsum = 0.f;
        #pragma unroll
        for (int dd = 0; dd < 8; dd++) dsum += sh[local][head * 8 + dd] * av[head * 8 + dd];
        if (vec == 0) o0[(size_t)node * 4 + head] = __float2half(dsum);
        else if (vec == 1) o1[(size_t)node * 4 + head] = dsum;
        else if (vec == 2) o2[(size_t)node * 4 + head] = __float2half(dsum);
        else o3[(size_t)node * 4 + head] = dsum;
    }
}

// ================= merged CSR aggregation (all rels) + fused semantic score =================
// 16 lanes/dst; clamped unroll-4 edge loop (parallel loads), fp16 asrc, int indexing.
__global__ void agg_all_kernel(
    const int* __restrict__ rowptr, const int* __restrict__ col,
    const __half* __restrict__ h_a, const __half* __restrict__ h_t,
    const __half* __restrict__ asrc0, const float* __restrict__ adst0,
    const __half* __restrict__ asrc1, const float* __restrict__ adst1,
    const __half* __restrict__ asrc2, const float* __restrict__ adst2,
    __half* __restrict__ agg_t0, __half* __restrict__ agg_a, __half* __restrict__ agg_t2,
    const float* __restrict__ kw, const float* __restrict__ kb, const float* __restrict__ q,
    float* __restrict__ scoreOut, int NT, int NA, int mode, int nRows) {
    __shared__ float sW[1024];
    __shared__ float sb[32];
    __shared__ float sq[32];
    __shared__ float sScore[2];
    int tid = threadIdx.x;
    bool doScore = (mode != 2);
    if (doScore) {
        for (int i = tid; i < 1024; i += 256) sW[i] = kw[i];
        if (tid < 32) { sb[tid] = kb[tid]; sq[tid] = q[tid]; }
        if (tid < 2) sScore[tid] = 0.f;
        __syncthreads();
    }
    int lane = tid & 15;
    int head = lane >> 2, f0 = lane * 2;
    long stride = (long)gridDim.x * 16;
    for (long gi = (long)blockIdx.x * 16 + (tid >> 4); gi < (long)nRows; gi += stride) {
        int row;
        if (mode == 0) row = (int)gi;
        else if (mode == 1) row = (gi < NT) ? (int)gi : (int)(gi + NA);
        else row = NT + (int)gi;
        int rel, dst;
        const __half* h; const __half* asrc; const float* adp; __half* agg;
        if (row < NT)           { rel = 0; dst = row;           h = h_a; asrc = asrc0; adp = adst0; agg = agg_t0; }
        else if (row < NT + NA) { rel = 1; dst = row - NT;      h = h_t; asrc = asrc1; adp = adst1; agg = agg_a; }
        else                    { rel = 2; dst = row - NT - NA; h = h_t; asrc = asrc2; adp = adst2; agg = agg_t2; }
        float ad = adp[dst * 4 + head];
        int e0 = rowptr[row], e1 = rowptr[row + 1];
        float accx = 0.f, accy = 0.f, den = 0.f;
        for (int e = e0; e < e1; e += 4) {
            int s0 = col[e];
            int s1 = (e + 1 < e1) ? col[e + 1] : s0;
            int s2 = (e + 2 < e1) ? col[e + 2] : s0;
            int s3 = (e + 3 < e1) ? col[e + 3] : s0;
            float as0 = __half2float(asrc[s0 * 4 + head]);
            float as1 = __half2float(asrc[s1 * 4 + head]);
            float as2 = __half2float(asrc[s2 * 4 + head]);
            float as3 = __half2float(asrc[s3 * 4 + head]);
            __half2 hv0 = *(const __half2*)(h + s0 * 32 + f0);
            __half2 hv1 = *(const __half2*)(h + s1 * 32 + f0);
            __half2 hv2 = *(const __half2*)(h + s2 * 32 + f0);
            __half2 hv3 = *(const __half2*)(h + s3 * 32 + f0);
            float t0 = as0 + ad; t0 = t0 > 0.f ? t0 : 0.2f * t0;
            float t1 = as1 + ad; t1 = t1 > 0.f ? t1 : 0.2f * t1;
            float t2 = as2 + ad; t2 = t2 > 0.f ? t2 : 0.2f * t2;
            float t3 = as3 + ad; t3 = t3 > 0.f ? t3 : 0.2f * t3;
            float ex0 = __expf(t0);
            float ex1 = (e + 1 < e1) ? __expf(t1) : 0.f;
            float ex2 = (e + 2 < e1) ? __expf(t2) : 0.f;
            float ex3 = (e + 3 < e1) ? __expf(t3) : 0.f;
            den += (ex0 + ex1) + (ex2 + ex3);
            float2 hf0 = __half22float2(hv0), hf1 = __half22float2(hv1);
            float2 hf2 = __half22float2(hv2), hf3 = __half22float2(hv3);
            accx += (ex0 * hf0.x + ex1 * hf1.x) + (ex2 * hf2.x + ex3 * hf3.x);
            accy += (ex0 * hf0.y + ex1 * hf1.y) + (ex2 * hf2.y + ex3 * hf3.y);
        }
        float r = 1.f / (den + 1e-16f);
        float vx = accx * r, vy = accy * r;
        __half2 o; o.x = __float2half(vx); o.y = __float2half(vy);
        *(__half2*)(agg + dst * 32 + f0) = o;
        if (doScore && rel != 1) {
            float r0 = fmaxf(vx, 0.f), r1 = fmaxf(vy, 0.f);
            float y0 = sb[f0], y1 = sb[f0 + 1];
            #pragma unroll
            for (int k = 0; k < 16; k++) {
                float rx = __shfl(r0, k, 16);
                float ry = __shfl(r1, k, 16);
                y0 += rx * sW[(2 * k) * 32 + f0]     + ry * sW[(2 * k + 1) * 32 + f0];
                y1 += rx * sW[(2 * k) * 32 + f0 + 1] + ry * sW[(2 * k + 1) * 32 + f0 + 1];
            }
            float sacc = sq[f0] * fast_tanh(y0) + sq[f0 + 1] * fast_tanh(y1);
            #pragma unroll
            for (int m = 1; m < 16; m <<= 1) sacc += __shfl_xor(sacc, m, 16);
            if (lane == 0) atomicAdd(&sScore[rel == 2 ? 1 : 0], sacc);
        }
    }
    if (doScore) {
        __syncthreads();
        if (tid < 2) unsafeAtomicAdd(scoreOut + tid, sScore[tid]);
    }
}

// ================= fused combine(layer l) + projection(layer l+1), 16 nodes/block =================
__global__ void combineproj_kernel(
    const __half* __restrict__ agg_a, const __half* __restrict__ agg_t0, const __half* __restrict__ agg_t2,
    float* __restrict__ xa, float* __restrict__ xt,
    const float* __restrict__ ln_ag, const float* __restrict__ ln_ab,
    const float* __restrict__ ln_tg, const float* __restrict__ ln_tb,
    const float* __restrict__ scores, float invNT,
    const float* __restrict__ Wa, const float* __restrict__ Ba,
    const float* __restrict__ Wt, const float* __restrict__ Bt,
    const float* __restrict__ as0, const float* __restrict__ ad1,
    const float* __restrict__ as1, const float* __restrict__ ad0,
    const float* __restrict__ as2, const float* __restrict__ ad2,
    __half* __restrict__ h_a, __half* __restrict__ h_t,
    __half* __restrict__ o_as0, float* __restrict__ o_ad1,
    __half* __restrict__ o_as1, float* __restrict__ o_ad0,
    __half* __restrict__ o_as2, float* __restrict__ o_ad2,
    int NA_, int NT_, int nbA16, int lastProj) {
    __shared__ float sW[1024];
    __shared__ float sv[5][32];
    __shared__ float sbp[32];
    __shared__ float sh[16][33];
    int tid = threadIdx.x;
    bool isA = blockIdx.x < nbA16;
    const float* W = isA ? Wa : Wt;
    for (int i = tid; i < 1024; i += 256) sW[i] = W[i];
    if (tid < 32) {
        sbp[tid] = (isA ? Ba : Bt)[tid];
        sv[1][tid] = (isA ? as0 : as1)[tid];
        sv[2][tid] = (isA ? ad1 : ad0)[tid];
        if (!isA) { sv[3][tid] = as2[tid]; sv[4][tid] = ad2[tid]; }
    }
    int local = tid >> 5, f = tid & 31;
    int n = isA ? NA_ : NT_;
    int base = (isA ? blockIdx.x : blockIdx.x - nbA16) * 16;
    int node0 = base + local, node1 = base + local + 8;
    float wsem0 = 0.f, wsem2 = 0.f;
    if (!isA) {
        float s0 = scores[0] * invNT, s2 = scores[1] * invNT;
        float mx = fmaxf(s0, s2);
        float e0 = __expf(s0 - mx), e2 = __expf(s2 - mx);
        float inv_s = 1.f / (e0 + e2);
        wsem0 = e0 * inv_s; wsem2 = e2 * inv_s;
    }
    const float* lng = isA ? ln_ag : ln_tg;
    const float* lnb = isA ? ln_ab : ln_tb;
    float gln = lng[f], bln = lnb[f];
    float ln0 = 0.f, ln1 = 0.f;
    if (node0 < n) {
        float v;
        if (isA) {
            v = fmaxf(__half2float(agg_a[(size_t)node0 * 32 + f]), 0.f) + xa[(size_t)node0 * 32 + f];
        } else {
            float a0 = fmaxf(__half2float(agg_t0[(size_t)node0 * 32 + f]), 0.f);
            float a2 = fmaxf(__half2float(agg_t2[(size_t)node0 * 32 + f]), 0.f);
            v = fmaxf(wsem0 * a0 + wsem2 * a2, 0.f) + xt[(size_t)node0 * 32 + f];
        }
        float m = v;
        #pragma unroll
        for (int mask = 1; mask < 32; mask <<= 1) m += __shfl_xor(m, mask, 64);
        m *= (1.f / 32.f);
        float d = v - m;
        float var = d * d;
        #pragma unroll
        for (int mask = 1; mask < 32; mask <<= 1) var += __shfl_xor(var, mask, 64);
        var *= (1.f / 32.f);
        ln0 = d * (1.f / sqrtf(var + 1e-5f)) * gln + bln;
        if (isA) xa[(size_t)node0 * 32 + f] = ln0;
        else if (!lastProj) xt[(size_t)node0 * 32 + f] = ln0;
    }
    if (node1 < n) {
        float v;
        if (isA) {
            v = fmaxf(__half2float(agg_a[(size_t)node1 * 32 + f]), 0.f) + xa[(size_t)node1 * 32 + f];
        } else {
            float a0 = fmaxf(__half2float(agg_t0[(size_t)node1 * 32 + f]), 0.f);
            float a2 = fmaxf(__half2float(agg_t2[(size_t)node1 * 32 + f]), 0.f);
            v = fmaxf(wsem0 * a0 + wsem2 * a2, 0.f) + xt[(size_t)node1 * 32 + f];
        }
        float m = v;
        #pragma unroll
        for (int mask = 1; mask < 32; mask <<= 1) m += __shfl_xor(m, mask, 64);
        m *= (1.f / 32.f);
        float d = v - m;
        float var = d * d;
        #pragma unroll
        for (int mask = 1; mask < 32; mask <<= 1) var += __shfl_xor(var, mask, 64);
        var *= (1.f / 32.f);
        ln1 = d * (1.f / sqrtf(var + 1e-5f)) * gln + bln;
        if (isA) xa[(size_t)node1 * 32 + f] = ln1;
        else if (!lastProj) xt[(size_t)node1 * 32 + f] = ln1;
    }
    sh[local][f] = ln0;
    sh[local + 8][f] = ln1;
    __syncthreads();
    float acc0 = sbp[f], acc1 = sbp[f];
    #pragma unroll
    for (int k = 0; k < 32; k++) {
        float w = sW[k * 32 + f];
        acc0 += sh[local][k] * w;
        acc1 += sh[local + 8][k] * w;
    }
    bool writeH = (!isA || !lastProj);
    __half* hptr = isA ? h_a : h_t;
    if (writeH) {
        if (node0 < n) hptr[(size_t)node0 * 32 + f] = __float2half(acc0);
        if (node1 < n) hptr[(size_t)node1 * 32 + f] = __float2half(acc1);
    }
    __syncthreads();
    sh[local][f] = acc0;
    sh[local + 8][f] = acc1;
    __syncthreads();
    int nvec = isA ? 8 : 16;
    if (f < nvec) {
        int vec = f >> 2, head = f & 3;
        bool need = !lastProj || (isA ? (vec == 1) : (vec == 0));
        if (need) {
            const float* av = sv[1 + vec];
            float d0 = 0.f, d1 = 0.f;
            #pragma unroll
            for (int dd = 0; dd < 8; dd++) {
                float a = av[head * 8 + dd];
                d0 += sh[local][head * 8 + dd] * a;
                d1 += sh[local + 8][head * 8 + dd] * a;
            }
            bool isHalf = isA ? (vec == 0) : (vec == 0 || vec == 2);
            if (isHalf) {
                __half* op = isA ? o_as0 : (vec == 0 ? o_as1 : o_as2);
                if (node0 < n) op[(size_t)node0 * 4 + head] = __float2half(d0);
                if (node1 < n) op[(size_t)node1 * 4 + head] = __float2half(d1);
            } else {
                float* op = isA ? o_ad1 : (vec == 1 ? o_ad0 : o_ad2);
                if (node0 < n) op[(size_t)node0 * 4 + head] = d0;
                if (node1 < n) op[(size_t)node1 * 4 + head] = d1;
            }
        }
    }
}

// ================= layer-3 combine_addr + output head =================
__global__ void combine_final_kernel(const __half* __restrict__ agg_a, const float* __restrict__ xa,
                                     const float* __restrict__ g, const float* __restrict__ bt,
                                     const float* __restrict__ lw, const float* __restrict__ lb,
                                     float* __restrict__ out, int n) {
    int tid = threadIdx.x;
    int local = tid >> 5, f = tid & 31;
    int node = blockIdx.x * 8 + local;
    if (node >= n) return;
    float a = __half2float(agg_a[(size_t)node * 32 + f]);
    float v = fmaxf(a, 0.f) + xa[(size_t)node * 32 + f];
    float m = v;
    #pragma unroll
    for (int mask = 1; mask < 32; mask <<= 1) m += __shfl_xor(m, mask, 64);
    m *= (1.f / 32.f);
    float d = v - m;
    float var = d * d;
    #pragma unroll
    for (int mask = 1; mask < 32; mask <<= 1) var += __shfl_xor(var, mask, 64);
    var *= (1.f / 32.f);
    float inv = 1.f / sqrtf(var + 1e-5f);
    float ln = d * inv * g[f] + bt[f];
    float p0 = ln * lw[f * 2 + 0];
    float p1 = ln * lw[f * 2 + 1];
    #pragma unroll
    for (int mask = 1; mask < 32; mask <<= 1) {
        p0 += __shfl_xor(p0, mask, 64);
        p1 += __shfl_xor(p1, mask, 64);
    }
    if (f == 0) {
        out[(size_t)node * 2 + 0] = p0 + lb[0];
        out[(size_t)node * 2 + 1] = p1 + lb[1];
    }
}

extern "C" void kernel_launch(void* const* d_in, const int* in_sizes, int n_in,
                              void* d_out, int out_size, void* d_ws, size_t ws_size,
                              hipStream_t stream) {
    const float* x_addr = (const float*)d_in[0];
    const float* x_tx   = (const float*)d_in[1];
    const int* ei_in    = (const int*)d_in[2];
    const int* ei_out   = (const int*)d_in[3];
    const int* ei_sp    = (const int*)d_in[4];
    const float* enc_w_addr = (const float*)d_in[5];
    const float* enc_b_addr = (const float*)d_in[6];
    const float* enc_w_tx   = (const float*)d_in[7];
    const float* enc_b_tx   = (const float*)d_in[8];
    const float* ln_ag = (const float*)d_in[9];
    const float* ln_ab = (const float*)d_in[10];
    const float* ln_tg = (const float*)d_in[11];
    const float* ln_tb = (const float*)d_in[12];
    const float* pw_a = (const float*)d_in[13];
    const float* pb_a = (const float*)d_in[14];
    const float* pw_t = (const float*)d_in[15];
    const float* pb_t = (const float*)d_in[16];
    const float* att_src = (const float*)d_in[17];
    const float* att_dst = (const float*)d_in[18];
    const float* klw = (const float*)d_in[19];
    const float* klb = (const float*)d_in[20];
    const float* qv  = (const float*)d_in[21];
    const float* lin_w = (const float*)d_in[22];
    const float* lin_b = (const float*)d_in[23];
    float* out = (float*)d_out;

    const int NA = in_sizes[0] / 53;
    const int NT = in_sizes[1] / 6;
    const int E_IN = in_sizes[2] / 2;
    const int E_OUT = in_sizes[3] / 2;
    const int E_SP = in_sizes[4] / 2;
    const int E_TOT = E_IN + E_OUT + E_SP;
    const int NCAT = NT + NA + NT;

    size_t off = 0;
    float* base = (float*)d_ws;
    auto alloc = [&](size_t nfloats) {
        float* p = base + off;
        off += (nfloats + 63) & ~(size_t)63;
        return p;
    };
    float* xa      = alloc((size_t)NA * 32);
    float* xt      = alloc((size_t)NT * 32);
    float* agg_a_f = alloc((size_t)NA * 16);
    float* agg_t0f = alloc((size_t)NT * 16);
    float* agg_t2f = alloc((size_t)NT * 16);
    float* h_t_f   = alloc((size_t)NT * 16);
    float* asrc0a  = alloc((size_t)NA * 2);   // fp16 x4 per node
    float* adst1a  = alloc((size_t)NA * 4);
    float* asrc1t  = alloc((size_t)NT * 2);   // fp16
    float* adst0t  = alloc((size_t)NT * 4);
    float* asrc2t  = alloc((size_t)NT * 2);   // fp16
    float* adst2t  = alloc((size_t)NT * 4);
    int* rowptrAll = (int*)alloc((size_t)NCAT + 64);
    int* colAll    = (int*)alloc((size_t)E_TOT);
    size_t tmp_span = (((size_t)NCAT + 63) & ~(size_t)63) + 1088 + 64;
    int* tmp       = (int*)alloc((size_t)NCAT);
    int* bsum      = (int*)alloc(1088);
    float* scores  = alloc(64);

    size_t ha_floats = (((size_t)NA * 16) + 63) & ~(size_t)63;
    bool roomy = ((off + ha_floats) * sizeof(float)) <= ws_size;
    float* h_a_f = roomy ? alloc((size_t)NA * 16) : agg_a_f;

    __half* agg_a  = (__half*)agg_a_f;
    __half* agg_t0 = (__half*)agg_t0f;
    __half* agg_t2 = (__half*)agg_t2f;
    __half* h_t    = (__half*)h_t_f;
    __half* h_a    = (__half*)h_a_f;
    __half* has0   = (__half*)asrc0a;
    __half* has1   = (__half*)asrc1t;
    __half* has2   = (__half*)asrc2t;

    dim3 blk(256);
    int nbA8 = (NA + 7) / 8, nbT8 = (NT + 7) / 8;
    int nbA16 = (NA + 15) / 16, nbT16 = (NT + 15) / 16;
    int nbE = (E_TOT + 255) / 256;
    int nbScan = (NCAT + 1023) / 1024;

    // ---- CSR build (once, reused by all layers) ----
    zero_int_kernel<<<2048, blk, 0, stream>>>(tmp, (long)tmp_span);
    hist_kernel<<<nbE, blk, 0, stream>>>(ei_in, ei_out, ei_sp, E_IN, E_OUT, E_SP, NT, NA, tmp, E_TOT);
    scan1_kernel<<<nbScan, blk, 0, stream>>>(tmp, rowptrAll, bsum, NCAT);
    scan2_kernel<<<1, 1024, 0, stream>>>(bsum, nbScan);
    scan3_kernel<<<(NCAT + 255) / 256, blk, 0, stream>>>(rowptrAll, bsum, tmp, NCAT, E_TOT);
    scatter_kernel<<<nbE, blk, 0, stream>>>(ei_in, ei_out, ei_sp, E_IN, E_OUT, E_SP, NT, NA, tmp, colAll, E_TOT);

    // ---- fused encoder + layer-0 projection ----
    encproj_addr_kernel<<<nbA8, blk, 0, stream>>>(
        x_addr, enc_w_addr, enc_b_addr, pw_a, pb_a,
        att_src + 0 * 32, att_dst + 1 * 32,
        xa, h_a, has0, adst1a, NA);
    encproj_tx_kernel<<<nbT8, blk, 0, stream>>>(
        x_tx, enc_w_tx, enc_b_tx, pw_t, pb_t,
        att_src + 1 * 32, att_dst + 0 * 32, att_src + 2 * 32, att_dst + 2 * 32,
        xt, h_t, has1, adst0t, has2, adst2t, NT);

    auto agg_launch = [&](int mode, int nRows, const float* kw, const float* kb,
                          const float* q, float* sc) {
        int blocks = (nRows + 15) / 16;
        if (blocks > 2048) blocks = 2048;
        agg_all_kernel<<<blocks, blk, 0, stream>>>(
            rowptrAll, colAll, h_a, h_t,
            has0, adst0t, has1, adst1a, has2, adst2t,
            agg_t0, agg_a, agg_t2, kw, kb, q, sc, NT, NA, mode, nRows);
    };

    for (int l = 0; l < NLAYERS; l++) {
        bool last = (l == NLAYERS - 1);
        const float* kw = klw + l * 1024;
        const float* kb = klb + l * 32;
        const float* q  = qv + l * 32;
        float* sc = scores + 2 * l;
        if (!last) {
            if (roomy) {
                agg_launch(0, NCAT, kw, kb, q, sc);
            } else {
                agg_launch(1, 2 * NT, kw, kb, q, sc);
                agg_launch(2, NA, kw, kb, q, sc);
            }
            int lp = l + 1;
            combineproj_kernel<<<nbA16 + nbT16, blk, 0, stream>>>(
                agg_a, agg_t0, agg_t2, xa, xt,
                ln_ag, ln_ab, ln_tg, ln_tb,
                sc, 1.0f / (float)NT,
                pw_a + lp * 1024, pb_a + lp * 32, pw_t + lp * 1024, pb_t + lp * 32,
                att_src + (lp * 3 + 0) * 32, att_dst + (lp * 3 + 1) * 32,
                att_src + (lp * 3 + 1) * 32, att_dst + (lp * 3 + 0) * 32,
                att_src + (lp * 3 + 2) * 32, att_dst + (lp * 3 + 2) * 32,
                h_a, h_t,
                has0, adst1a, has1, adst0t, has2, adst2t,
                NA, NT, nbA16, lp == 3 ? 1 : 0);
        } else {
            agg_launch(2, NA, kw, kb, q, sc);
            combine_final_kernel<<<nbA8, blk, 0, stream>>>(agg_a, xa, ln_ag, ln_ab,
                                                           lin_w, lin_b, out, NA);
        }
    }
}

// Round 9
// 1268.761 us; speedup vs baseline: 1.4991x; 1.0824x over previous
//
#include <hip/hip_runtime.h>
#include <hip/hip_fp16.h>

#define NLAYERS 4

// ---------------- zero fill ----------------
__global__ void zero_int_kernel(int* __restrict__ p, long n) {
    long i = (long)blockIdx.x * 256 + threadIdx.x;
    long stride = (long)gridDim.x * 256;
    for (; i < n; i += stride) p[i] = 0;
}

__device__ __forceinline__ float fast_tanh(float y) {
    y = fminf(fmaxf(y, -15.f), 15.f);
    float t = __expf(2.f * y);
    return (t - 1.f) / (t + 1.f);
}

// ================= CSR build over concatenated dst space =================
// [0,NT) rel0 dsts | [NT,NT+NA) rel1 dsts | [NT+NA,NCAT) rel2 dsts
__device__ __forceinline__ int edge_row(const int* ei_in, const int* ei_out, const int* ei_sp,
                                        int E_IN, int E_OUT, int E_SP, int NT, int NA,
                                        int e, int* src) {
    if (e < E_IN) { *src = ei_in[e]; return ei_in[E_IN + e]; }
    if (e < E_IN + E_OUT) { int i = e - E_IN; *src = ei_out[i]; return NT + ei_out[E_OUT + i]; }
    int i = e - E_IN - E_OUT; *src = ei_sp[i]; return NT + NA + ei_sp[E_SP + i];
}

__global__ void hist_kernel(const int* __restrict__ ei_in, const int* __restrict__ ei_out,
                            const int* __restrict__ ei_sp, int E_IN, int E_OUT, int E_SP,
                            int NT, int NA, int* __restrict__ deg, int E_TOT) {
    int e = blockIdx.x * 256 + threadIdx.x;
    if (e >= E_TOT) return;
    int s;
    int row = edge_row(ei_in, ei_out, ei_sp, E_IN, E_OUT, E_SP, NT, NA, e, &s);
    atomicAdd(&deg[row], 1);
}

__global__ void scan1_kernel(const int* __restrict__ deg, int* __restrict__ rowptr,
                             int* __restrict__ bsum, int n) {
    __shared__ int lds[256];
    int tid = threadIdx.x;
    int base = blockIdx.x * 1024;
    int v[4];
    int mysum = 0;
    #pragma unroll
    for (int j = 0; j < 4; j++) {
        int idx = base + tid * 4 + j;
        v[j] = (idx < n) ? deg[idx] : 0;
        mysum += v[j];
    }
    lds[tid] = mysum;
    __syncthreads();
    for (int off = 1; off < 256; off <<= 1) {
        int t = (tid >= off) ? lds[tid - off] : 0;
        __syncthreads();
        lds[tid] += t;
        __syncthreads();
    }
    int excl = lds[tid] - mysum;
    if (tid == 255) bsum[blockIdx.x] = lds[tid];
    int run = excl;
    #pragma unroll
    for (int j = 0; j < 4; j++) {
        int idx = base + tid * 4 + j;
        if (idx < n) rowptr[idx] = run;
        run += v[j];
    }
}

__global__ void scan2_kernel(int* __restrict__ bsum, int nb) {
    __shared__ int lds[1024];
    int tid = threadIdx.x;
    int v = (tid < nb) ? bsum[tid] : 0;
    lds[tid] = v;
    __syncthreads();
    for (int off = 1; off < 1024; off <<= 1) {
        int t = (tid >= off) ? lds[tid - off] : 0;
        __syncthreads();
        lds[tid] += t;
        __syncthreads();
    }
    if (tid < nb) bsum[tid] = lds[tid] - v;
}

__global__ void scan3_kernel(int* __restrict__ rowptr, const int* __restrict__ bsum,
                             int* __restrict__ cursor, int n, int E) {
    int i = blockIdx.x * 256 + threadIdx.x;
    if (i < n) {
        int r = rowptr[i] + bsum[i >> 10];
        rowptr[i] = r;
        cursor[i] = r;
    }
    if (i == 0) rowptr[n] = E;
}

__global__ void scatter_kernel(const int* __restrict__ ei_in, const int* __restrict__ ei_out,
                               const int* __restrict__ ei_sp, int E_IN, int E_OUT, int E_SP,
                               int NT, int NA, int* __restrict__ cursor, int* __restrict__ col,
                               int E_TOT) {
    int e = blockIdx.x * 256 + threadIdx.x;
    if (e >= E_TOT) return;
    int s;
    int row = edge_row(ei_in, ei_out, ei_sp, E_IN, E_OUT, E_SP, NT, NA, e, &s);
    int pos = atomicAdd(&cursor[row], 1);
    col[pos] = s;
}

// ================= fused encoder + layer-0 projection =================
__global__ void encproj_addr_kernel(const float* __restrict__ x,
                                    const float* __restrict__ We, const float* __restrict__ be,
                                    const float* __restrict__ Wp, const float* __restrict__ bp,
                                    const float* __restrict__ a0, const float* __restrict__ a1,
                                    float* __restrict__ xa, __half* __restrict__ h,
                                    __half* __restrict__ o0, float* __restrict__ o1, int n) {
    __shared__ float sWe[53 * 32];
    __shared__ float sW[1024];
    __shared__ float sv[3][32];
    __shared__ float sbp[32];
    __shared__ float sx[8][56];
    __shared__ float sh[8][33];
    int tid = threadIdx.x;
    for (int i = tid; i < 53 * 32; i += 256) sWe[i] = We[i];
    for (int i = tid; i < 1024; i += 256) sW[i] = Wp[i];
    if (tid < 32) { sv[0][tid] = be[tid]; sv[1][tid] = a0[tid]; sv[2][tid] = a1[tid]; sbp[tid] = bp[tid]; }
    int local = tid >> 5, f = tid & 31;
    int node = blockIdx.x * 8 + local;
    if (node < n) {
        for (int k = f; k < 53; k += 32) sx[local][k] = x[(size_t)node * 53 + k];
    }
    __syncthreads();
    float xe = 0.f;
    if (node < n) {
        float acc = sv[0][f];
        for (int k = 0; k < 53; k++) acc += sx[local][k] * sWe[k * 32 + f];
        xe = fmaxf(acc, 0.f);
        xa[(size_t)node * 32 + f] = xe;
    }
    sh[local][f] = xe;
    __syncthreads();
    float accp = 0.f;
    if (node < n) {
        accp = sbp[f];
        #pragma unroll
        for (int k = 0; k < 32; k++) accp += sh[local][k] * sW[k * 32 + f];
        h[(size_t)node * 32 + f] = __float2half(accp);
    }
    __syncthreads();
    sh[local][f] = accp;
    __syncthreads();
    if (node < n && f < 8) {
        int vec = f >> 2, head = f & 3;
        const float* av = sv[1 + vec];
        float dsum = 0.f;
        #pragma unroll
        for (int dd = 0; dd < 8; dd++) dsum += sh[local][head * 8 + dd] * av[head * 8 + dd];
        if (vec == 0) o0[(size_t)node * 4 + head] = __float2half(dsum);
        else o1[(size_t)node * 4 + head] = dsum;
    }
}

__global__ void encproj_tx_kernel(const float* __restrict__ x,
                                  const float* __restrict__ We, const float* __restrict__ be,
                                  const float* __restrict__ Wp, const float* __restrict__ bp,
                                  const float* __restrict__ a0, const float* __restrict__ a1,
                                  const float* __restrict__ a2, const float* __restrict__ a3,
                                  float* __restrict__ xt, __half* __restrict__ h,
                                  __half* __restrict__ o0, float* __restrict__ o1,
                                  __half* __restrict__ o2, float* __restrict__ o3, int n) {
    __shared__ float sWe[6 * 32];
    __shared__ float sW[1024];
    __shared__ float sv[5][32];
    __shared__ float sbp[32];
    __shared__ float sx[8][8];
    __shared__ float sh[8][33];
    int tid = threadIdx.x;
    for (int i = tid; i < 6 * 32; i += 256) sWe[i] = We[i];
    for (int i = tid; i < 1024; i += 256) sW[i] = Wp[i];
    if (tid < 32) {
        sv[0][tid] = be[tid]; sv[1][tid] = a0[tid]; sv[2][tid] = a1[tid];
        sv[3][tid] = a2[tid]; sv[4][tid] = a3[tid]; sbp[tid] = bp[tid];
    }
    int local = tid >> 5, f = tid & 31;
    int node = blockIdx.x * 8 + local;
    if (node < n && f < 6) sx[local][f] = x[(size_t)node * 6 + f];
    __syncthreads();
    float xe = 0.f;
    if (node < n) {
        float acc = sv[0][f];
        #pragma unroll
        for (int k = 0; k < 6; k++) acc += sx[local][k] * sWe[k * 32 + f];
        xe = fmaxf(acc, 0.f);
        xt[(size_t)node * 32 + f] = xe;
    }
    sh[local][f] = xe;
    __syncthreads();
    float accp = 0.f;
    if (node < n) {
        accp = sbp[f];
        #pragma unroll
        for (int k = 0; k < 32; k++) accp += sh[local][k] * sW[k * 32 + f];
        h[(size_t)node * 32 + f] = __float2half(accp);
    }
    __syncthreads();
    sh[local][f] = accp;
    __syncthreads();
    if (node < n && f < 16) {
        int vec = f >> 2, head = f & 3;
        const float* av = sv[1 + vec];
        float dsum = 0.f;
        #pragma unroll
        for (int dd = 0; dd < 8; dd++) dsum += sh[local][head * 8 + dd] * av[head * 8 + dd];
        if (vec == 0) o0[(size_t)node * 4 + head] = __float2half(dsum);
        else if (vec == 1) o1[(size_t)node * 4 + head] = dsum;
        else if (vec == 2) o2[(size_t)node * 4 + head] = __float2half(dsum);
        else o3[(size_t)node * 4 + head] = dsum;
    }
}

// ================= merged CSR aggregation (all rels) + fused semantic score =================
// 8 lanes/dst (lane owns 4 features, single head); packed hfma2 accumulation;
// clamped unroll-4 edge loop; fp16 asrc; 32-bit indexing.
__global__ void agg_all_kernel(
    const int* __restrict__ rowptr, const int* __restrict__ col,
    const __half* __restrict__ h_a, const __half* __restrict__ h_t,
    const __half* __restrict__ asrc0, const float* __restrict__ adst0,
    const __half* __restrict__ asrc1, const float* __restrict__ adst1,
    const __half* __restrict__ asrc2, const float* __restrict__ adst2,
    __half* __restrict__ agg_t0, __half* __restrict__ agg_a, __half* __restrict__ agg_t2,
    const float* __restrict__ kw, const float* __restrict__ kb, const float* __restrict__ q,
    float* __restrict__ scoreOut, int NT, int NA, int mode, int nRows) {
    __shared__ float sW[1024];
    __shared__ float sb[32];
    __shared__ float sq[32];
    __shared__ float sScore[2];
    int tid = threadIdx.x;
    bool doScore = (mode != 2);
    if (doScore) {
        for (int i = tid; i < 1024; i += 256) sW[i] = kw[i];
        if (tid < 32) { sb[tid] = kb[tid]; sq[tid] = q[tid]; }
        if (tid < 2) sScore[tid] = 0.f;
        __syncthreads();
    }
    int lane = tid & 7;            // 8 lanes per dst
    int head = lane >> 1;          // features 4*lane..4*lane+3 all in this head
    int f0 = lane * 4;
    long stride = (long)gridDim.x * 32;
    for (long gi = (long)blockIdx.x * 32 + (tid >> 3); gi < (long)nRows; gi += stride) {
        int row;
        if (mode == 0) row = (int)gi;
        else if (mode == 1) row = (gi < NT) ? (int)gi : (int)(gi + NA);
        else row = NT + (int)gi;
        int rel, dst;
        const __half* h; const __half* asrc; const float* adp; __half* agg;
        if (row < NT)           { rel = 0; dst = row;           h = h_a; asrc = asrc0; adp = adst0; agg = agg_t0; }
        else if (row < NT + NA) { rel = 1; dst = row - NT;      h = h_t; asrc = asrc1; adp = adst1; agg = agg_a; }
        else                    { rel = 2; dst = row - NT - NA; h = h_t; asrc = asrc2; adp = adst2; agg = agg_t2; }
        float ad = adp[dst * 4 + head];
        int e0 = rowptr[row], e1 = rowptr[row + 1];
        __half2 acc0 = __floats2half2_rn(0.f, 0.f);
        __half2 acc1 = acc0;
        float den = 0.f;
        for (int e = e0; e < e1; e += 4) {
            int s0 = col[e];
            int s1 = (e + 1 < e1) ? col[e + 1] : s0;
            int s2 = (e + 2 < e1) ? col[e + 2] : s0;
            int s3 = (e + 3 < e1) ? col[e + 3] : s0;
            float as0 = __half2float(asrc[s0 * 4 + head]);
            float as1 = __half2float(asrc[s1 * 4 + head]);
            float as2 = __half2float(asrc[s2 * 4 + head]);
            float as3 = __half2float(asrc[s3 * 4 + head]);
            float2 r0 = *(const float2*)(h + s0 * 32 + f0);
            float2 r1 = *(const float2*)(h + s1 * 32 + f0);
            float2 r2 = *(const float2*)(h + s2 * 32 + f0);
            float2 r3 = *(const float2*)(h + s3 * 32 + f0);
            float t0 = as0 + ad; t0 = t0 > 0.f ? t0 : 0.2f * t0;
            float t1 = as1 + ad; t1 = t1 > 0.f ? t1 : 0.2f * t1;
            float t2 = as2 + ad; t2 = t2 > 0.f ? t2 : 0.2f * t2;
            float t3 = as3 + ad; t3 = t3 > 0.f ? t3 : 0.2f * t3;
            float ex0 = __expf(t0);
            float ex1 = (e + 1 < e1) ? __expf(t1) : 0.f;
            float ex2 = (e + 2 < e1) ? __expf(t2) : 0.f;
            float ex3 = (e + 3 < e1) ? __expf(t3) : 0.f;
            den += (ex0 + ex1) + (ex2 + ex3);
            __half2 eh0 = __float2half2_rn(ex0), eh1 = __float2half2_rn(ex1);
            __half2 eh2 = __float2half2_rn(ex2), eh3 = __float2half2_rn(ex3);
            acc0 = __hfma2(eh0, *(__half2*)&r0.x, acc0);
            acc1 = __hfma2(eh0, *(__half2*)&r0.y, acc1);
            acc0 = __hfma2(eh1, *(__half2*)&r1.x, acc0);
            acc1 = __hfma2(eh1, *(__half2*)&r1.y, acc1);
            acc0 = __hfma2(eh2, *(__half2*)&r2.x, acc0);
            acc1 = __hfma2(eh2, *(__half2*)&r2.y, acc1);
            acc0 = __hfma2(eh3, *(__half2*)&r3.x, acc0);
            acc1 = __hfma2(eh3, *(__half2*)&r3.y, acc1);
        }
        float r = 1.f / (den + 1e-16f);
        float2 a0 = __half22float2(acc0), a1 = __half22float2(acc1);
        float v0 = a0.x * r, v1 = a0.y * r, v2 = a1.x * r, v3 = a1.y * r;
        float2 opack;
        __half2 o0 = __floats2half2_rn(v0, v1), o1 = __floats2half2_rn(v2, v3);
        opack.x = *(float*)&o0; opack.y = *(float*)&o1;
        *(float2*)(agg + dst * 32 + f0) = opack;
        if (doScore && rel != 1) {
            float rv0 = fmaxf(v0, 0.f), rv1 = fmaxf(v1, 0.f);
            float rv2 = fmaxf(v2, 0.f), rv3 = fmaxf(v3, 0.f);
            float y0 = sb[f0], y1 = sb[f0 + 1], y2 = sb[f0 + 2], y3 = sb[f0 + 3];
            #pragma unroll
            for (int g = 0; g < 8; g++) {
                float c0 = __shfl(rv0, g, 8);
                float c1 = __shfl(rv1, g, 8);
                float c2 = __shfl(rv2, g, 8);
                float c3 = __shfl(rv3, g, 8);
                int kb4 = g * 4;
                y0 += c0 * sW[(kb4 + 0) * 32 + f0] + c1 * sW[(kb4 + 1) * 32 + f0]
                    + c2 * sW[(kb4 + 2) * 32 + f0] + c3 * sW[(kb4 + 3) * 32 + f0];
                y1 += c0 * sW[(kb4 + 0) * 32 + f0 + 1] + c1 * sW[(kb4 + 1) * 32 + f0 + 1]
                    + c2 * sW[(kb4 + 2) * 32 + f0 + 1] + c3 * sW[(kb4 + 3) * 32 + f0 + 1];
                y2 += c0 * sW[(kb4 + 0) * 32 + f0 + 2] + c1 * sW[(kb4 + 1) * 32 + f0 + 2]
                    + c2 * sW[(kb4 + 2) * 32 + f0 + 2] + c3 * sW[(kb4 + 3) * 32 + f0 + 2];
                y3 += c0 * sW[(kb4 + 0) * 32 + f0 + 3] + c1 * sW[(kb4 + 1) * 32 + f0 + 3]
                    + c2 * sW[(kb4 + 2) * 32 + f0 + 3] + c3 * sW[(kb4 + 3) * 32 + f0 + 3];
            }
            float sacc = sq[f0] * fast_tanh(y0) + sq[f0 + 1] * fast_tanh(y1)
                       + sq[f0 + 2] * fast_tanh(y2) + sq[f0 + 3] * fast_tanh(y3);
            #pragma unroll
            for (int m = 1; m < 8; m <<= 1) sacc += __shfl_xor(sacc, m, 8);
            if (lane == 0) atomicAdd(&sScore[rel == 2 ? 1 : 0], sacc);
        }
    }
    if (doScore) {
        __syncthreads();
        if (tid < 2) unsafeAtomicAdd(scoreOut + tid, sScore[tid]);
    }
}

// ================= fused combine(layer l) + projection(layer l+1), 16 nodes/block =================
__global__ void combineproj_kernel(
    const __half* __restrict__ agg_a, const __half* __restrict__ agg_t0, const __half* __restrict__ agg_t2,
    float* __restrict__ xa, float* __restrict__ xt,
    const float* __restrict__ ln_ag, const float* __restrict__ ln_ab,
    const float* __restrict__ ln_tg, const float* __restrict__ ln_tb,
    const float* __restrict__ scores, float invNT,
    const float* __restrict__ Wa, const float* __restrict__ Ba,
    const float* __restrict__ Wt, const float* __restrict__ Bt,
    const float* __restrict__ as0, const float* __restrict__ ad1,
    const float* __restrict__ as1, const float* __restrict__ ad0,
    const float* __restrict__ as2, const float* __restrict__ ad2,
    __half* __restrict__ h_a, __half* __restrict__ h_t,
    __half* __restrict__ o_as0, float* __restrict__ o_ad1,
    __half* __restrict__ o_as1, float* __restrict__ o_ad0,
    __half* __restrict__ o_as2, float* __restrict__ o_ad2,
    int NA_, int NT_, int nbA16, int lastProj) {
    __shared__ float sW[1024];
    __shared__ float sv[5][32];
    __shared__ float sbp[32];
    __shared__ float sh[16][33];
    int tid = threadIdx.x;
    bool isA = blockIdx.x < nbA16;
    const float* W = isA ? Wa : Wt;
    for (int i = tid; i < 1024; i += 256) sW[i] = W[i];
    if (tid < 32) {
        sbp[tid] = (isA ? Ba : Bt)[tid];
        sv[1][tid] = (isA ? as0 : as1)[tid];
        sv[2][tid] = (isA ? ad1 : ad0)[tid];
        if (!isA) { sv[3][tid] = as2[tid]; sv[4][tid] = ad2[tid]; }
    }
    int local = tid >> 5, f = tid & 31;
    int n = isA ? NA_ : NT_;
    int base = (isA ? blockIdx.x : blockIdx.x - nbA16) * 16;
    int node0 = base + local, node1 = base + local + 8;
    float wsem0 = 0.f, wsem2 = 0.f;
    if (!isA) {
        float s0 = scores[0] * invNT, s2 = scores[1] * invNT;
        float mx = fmaxf(s0, s2);
        float e0 = __expf(s0 - mx), e2 = __expf(s2 - mx);
        float inv_s = 1.f / (e0 + e2);
        wsem0 = e0 * inv_s; wsem2 = e2 * inv_s;
    }
    const float* lng = isA ? ln_ag : ln_tg;
    const float* lnb = isA ? ln_ab : ln_tb;
    float gln = lng[f], bln = lnb[f];
    float ln0 = 0.f, ln1 = 0.f;
    if (node0 < n) {
        float v;
        if (isA) {
            v = fmaxf(__half2float(agg_a[(size_t)node0 * 32 + f]), 0.f) + xa[(size_t)node0 * 32 + f];
        } else {
            float a0 = fmaxf(__half2float(agg_t0[(size_t)node0 * 32 + f]), 0.f);
            float a2 = fmaxf(__half2float(agg_t2[(size_t)node0 * 32 + f]), 0.f);
            v = fmaxf(wsem0 * a0 + wsem2 * a2, 0.f) + xt[(size_t)node0 * 32 + f];
        }
        float m = v;
        #pragma unroll
        for (int mask = 1; mask < 32; mask <<= 1) m += __shfl_xor(m, mask, 64);
        m *= (1.f / 32.f);
        float d = v - m;
        float var = d * d;
        #pragma unroll
        for (int mask = 1; mask < 32; mask <<= 1) var += __shfl_xor(var, mask, 64);
        var *= (1.f / 32.f);
        ln0 = d * (1.f / sqrtf(var + 1e-5f)) * gln + bln;
        if (isA) xa[(size_t)node0 * 32 + f] = ln0;
        else if (!lastProj) xt[(size_t)node0 * 32 + f] = ln0;
    }
    if (node1 < n) {
        float v;
        if (isA) {
            v = fmaxf(__half2float(agg_a[(size_t)node1 * 32 + f]), 0.f) + xa[(size_t)node1 * 32 + f];
        } else {
            float a0 = fmaxf(__half2float(agg_t0[(size_t)node1 * 32 + f]), 0.f);
            float a2 = fmaxf(__half2float(agg_t2[(size_t)node1 * 32 + f]), 0.f);
            v = fmaxf(wsem0 * a0 + wsem2 * a2, 0.f) + xt[(size_t)node1 * 32 + f];
        }
        float m = v;
        #pragma unroll
        for (int mask = 1; mask < 32; mask <<= 1) m += __shfl_xor(m, mask, 64);
        m *= (1.f / 32.f);
        float d = v - m;
        float var = d * d;
        #pragma unroll
        for (int mask = 1; mask < 32; mask <<= 1) var += __shfl_xor(var, mask, 64);
        var *= (1.f / 32.f);
        ln1 = d * (1.f / sqrtf(var + 1e-5f)) * gln + bln;
        if (isA) xa[(size_t)node1 * 32 + f] = ln1;
        else if (!lastProj) xt[(size_t)node1 * 32 + f] = ln1;
    }
    sh[local][f] = ln0;
    sh[local + 8][f] = ln1;
    __syncthreads();
    float acc0 = sbp[f], acc1 = sbp[f];
    #pragma unroll
    for (int k = 0; k < 32; k++) {
        float w = sW[k * 32 + f];
        acc0 += sh[local][k] * w;
        acc1 += sh[local + 8][k] * w;
    }
    bool writeH = (!isA || !lastProj);
    __half* hptr = isA ? h_a : h_t;
    if (writeH) {
        if (node0 < n) hptr[(size_t)node0 * 32 + f] = __float2half(acc0);
        if (node1 < n) hptr[(size_t)node1 * 32 + f] = __float2half(acc1);
    }
    __syncthreads();
    sh[local][f] = acc0;
    sh[local + 8][f] = acc1;
    __syncthreads();
    int nvec = isA ? 8 : 16;
    if (f < nvec) {
        int vec = f >> 2, head = f & 3;
        bool need = !lastProj || (isA ? (vec == 1) : (vec == 0));
        if (need) {
            const float* av = sv[1 + vec];
            float d0 = 0.f, d1 = 0.f;
            #pragma unroll
            for (int dd = 0; dd < 8; dd++) {
                float a = av[head * 8 + dd];
                d0 += sh[local][head * 8 + dd] * a;
                d1 += sh[local + 8][head * 8 + dd] * a;
            }
            bool isHalf = isA ? (vec == 0) : (vec == 0 || vec == 2);
            if (isHalf) {
                __half* op = isA ? o_as0 : (vec == 0 ? o_as1 : o_as2);
                if (node0 < n) op[(size_t)node0 * 4 + head] = __float2half(d0);
                if (node1 < n) op[(size_t)node1 * 4 + head] = __float2half(d1);
            } else {
                float* op = isA ? o_ad1 : (vec == 1 ? o_ad0 : o_ad2);
                if (node0 < n) op[(size_t)node0 * 4 + head] = d0;
                if (node1 < n) op[(size_t)node1 * 4 + head] = d1;
            }
        }
    }
}

// ================= layer-3 combine_addr + output head =================
__global__ void combine_final_kernel(const __half* __restrict__ agg_a, const float* __restrict__ xa,
                                     const float* __restrict__ g, const float* __restrict__ bt,
                                     const float* __restrict__ lw, const float* __restrict__ lb,
                                     float* __restrict__ out, int n) {
    int tid = threadIdx.x;
    int local = tid >> 5, f = tid & 31;
    int node = blockIdx.x * 8 + local;
    if (node >= n) return;
    float a = __half2float(agg_a[(size_t)node * 32 + f]);
    float v = fmaxf(a, 0.f) + xa[(size_t)node * 32 + f];
    float m = v;
    #pragma unroll
    for (int mask = 1; mask < 32; mask <<= 1) m += __shfl_xor(m, mask, 64);
    m *= (1.f / 32.f);
    float d = v - m;
    float var = d * d;
    #pragma unroll
    for (int mask = 1; mask < 32; mask <<= 1) var += __shfl_xor(var, mask, 64);
    var *= (1.f / 32.f);
    float inv = 1.f / sqrtf(var + 1e-5f);
    float ln = d * inv * g[f] + bt[f];
    float p0 = ln * lw[f * 2 + 0];
    float p1 = ln * lw[f * 2 + 1];
    #pragma unroll
    for (int mask = 1; mask < 32; mask <<= 1) {
        p0 += __shfl_xor(p0, mask, 64);
        p1 += __shfl_xor(p1, mask, 64);
    }
    if (f == 0) {
        out[(size_t)node * 2 + 0] = p0 + lb[0];
        out[(size_t)node * 2 + 1] = p1 + lb[1];
    }
}

extern "C" void kernel_launch(void* const* d_in, const int* in_sizes, int n_in,
                              void* d_out, int out_size, void* d_ws, size_t ws_size,
                              hipStream_t stream) {
    const float* x_addr = (const float*)d_in[0];
    const float* x_tx   = (const float*)d_in[1];
    const int* ei_in    = (const int*)d_in[2];
    const int* ei_out   = (const int*)d_in[3];
    const int* ei_sp    = (const int*)d_in[4];
    const float* enc_w_addr = (const float*)d_in[5];
    const float* enc_b_addr = (const float*)d_in[6];
    const float* enc_w_tx   = (const float*)d_in[7];
    const float* enc_b_tx   = (const float*)d_in[8];
    const float* ln_ag = (const float*)d_in[9];
    const float* ln_ab = (const float*)d_in[10];
    const float* ln_tg = (const float*)d_in[11];
    const float* ln_tb = (const float*)d_in[12];
    const float* pw_a = (const float*)d_in[13];
    const float* pb_a = (const float*)d_in[14];
    const float* pw_t = (const float*)d_in[15];
    const float* pb_t = (const float*)d_in[16];
    const float* att_src = (const float*)d_in[17];
    const float* att_dst = (const float*)d_in[18];
    const float* klw = (const float*)d_in[19];
    const float* klb = (const float*)d_in[20];
    const float* qv  = (const float*)d_in[21];
    const float* lin_w = (const float*)d_in[22];
    const float* lin_b = (const float*)d_in[23];
    float* out = (float*)d_out;

    const int NA = in_sizes[0] / 53;
    const int NT = in_sizes[1] / 6;
    const int E_IN = in_sizes[2] / 2;
    const int E_OUT = in_sizes[3] / 2;
    const int E_SP = in_sizes[4] / 2;
    const int E_TOT = E_IN + E_OUT + E_SP;
    const int NCAT = NT + NA + NT;

    size_t off = 0;
    float* base = (float*)d_ws;
    auto alloc = [&](size_t nfloats) {
        float* p = base + off;
        off += (nfloats + 63) & ~(size_t)63;
        return p;
    };
    float* xa      = alloc((size_t)NA * 32);
    float* xt      = alloc((size_t)NT * 32);
    float* agg_a_f = alloc((size_t)NA * 16);
    float* agg_t0f = alloc((size_t)NT * 16);
    float* agg_t2f = alloc((size_t)NT * 16);
    float* h_t_f   = alloc((size_t)NT * 16);
    float* asrc0a  = alloc((size_t)NA * 2);   // fp16 x4 per node
    float* adst1a  = alloc((size_t)NA * 4);
    float* asrc1t  = alloc((size_t)NT * 2);   // fp16
    float* adst0t  = alloc((size_t)NT * 4);
    float* asrc2t  = alloc((size_t)NT * 2);   // fp16
    float* adst2t  = alloc((size_t)NT * 4);
    int* rowptrAll = (int*)alloc((size_t)NCAT + 64);
    int* colAll    = (int*)alloc((size_t)E_TOT);
    size_t tmp_span = (((size_t)NCAT + 63) & ~(size_t)63) + 1088 + 64;
    int* tmp       = (int*)alloc((size_t)NCAT);
    int* bsum      = (int*)alloc(1088);
    float* scores  = alloc(64);

    size_t ha_floats = (((size_t)NA * 16) + 63) & ~(size_t)63;
    bool roomy = ((off + ha_floats) * sizeof(float)) <= ws_size;
    float* h_a_f = roomy ? alloc((size_t)NA * 16) : agg_a_f;

    __half* agg_a  = (__half*)agg_a_f;
    __half* agg_t0 = (__half*)agg_t0f;
    __half* agg_t2 = (__half*)agg_t2f;
    __half* h_t    = (__half*)h_t_f;
    __half* h_a    = (__half*)h_a_f;
    __half* has0   = (__half*)asrc0a;
    __half* has1   = (__half*)asrc1t;
    __half* has2   = (__half*)asrc2t;

    dim3 blk(256);
    int nbA8 = (NA + 7) / 8, nbT8 = (NT + 7) / 8;
    int nbA16 = (NA + 15) / 16, nbT16 = (NT + 15) / 16;
    int nbE = (E_TOT + 255) / 256;
    int nbScan = (NCAT + 1023) / 1024;

    // ---- CSR build (once, reused by all layers) ----
    zero_int_kernel<<<2048, blk, 0, stream>>>(tmp, (long)tmp_span);
    hist_kernel<<<nbE, blk, 0, stream>>>(ei_in, ei_out, ei_sp, E_IN, E_OUT, E_SP, NT, NA, tmp, E_TOT);
    scan1_kernel<<<nbScan, blk, 0, stream>>>(tmp, rowptrAll, bsum, NCAT);
    scan2_kernel<<<1, 1024, 0, stream>>>(bsum, nbScan);
    scan3_kernel<<<(NCAT + 255) / 256, blk, 0, stream>>>(rowptrAll, bsum, tmp, NCAT, E_TOT);
    scatter_kernel<<<nbE, blk, 0, stream>>>(ei_in, ei_out, ei_sp, E_IN, E_OUT, E_SP, NT, NA, tmp, colAll, E_TOT);

    // ---- fused encoder + layer-0 projection ----
    encproj_addr_kernel<<<nbA8, blk, 0, stream>>>(
        x_addr, enc_w_addr, enc_b_addr, pw_a, pb_a,
        att_src + 0 * 32, att_dst + 1 * 32,
        xa, h_a, has0, adst1a, NA);
    encproj_tx_kernel<<<nbT8, blk, 0, stream>>>(
        x_tx, enc_w_tx, enc_b_tx, pw_t, pb_t,
        att_src + 1 * 32, att_dst + 0 * 32, att_src + 2 * 32, att_dst + 2 * 32,
        xt, h_t, has1, adst0t, has2, adst2t, NT);

    auto agg_launch = [&](int mode, int nRows, const float* kw, const float* kb,
                          const float* q, float* sc) {
        int blocks = (nRows + 31) / 32;
        if (blocks > 2048) blocks = 2048;
        agg_all_kernel<<<blocks, blk, 0, stream>>>(
            rowptrAll, colAll, h_a, h_t,
            has0, adst0t, has1, adst1a, has2, adst2t,
            agg_t0, agg_a, agg_t2, kw, kb, q, sc, NT, NA, mode, nRows);
    };

    for (int l = 0; l < NLAYERS; l++) {
        bool last = (l == NLAYERS - 1);
        const float* kw = klw + l * 1024;
        const float* kb = klb + l * 32;
        const float* q  = qv + l * 32;
        float* sc = scores + 2 * l;
        if (!last) {
            if (roomy) {
                agg_launch(0, NCAT, kw, kb, q, sc);
            } else {
                agg_launch(1, 2 * NT, kw, kb, q, sc);
                agg_launch(2, NA, kw, kb, q, sc);
            }
            int lp = l + 1;
            combineproj_kernel<<<nbA16 + nbT16, blk, 0, stream>>>(
                agg_a, agg_t0, agg_t2, xa, xt,
                ln_ag, ln_ab, ln_tg, ln_tb,
                sc, 1.0f / (float)NT,
                pw_a + lp * 1024, pb_a + lp * 32, pw_t + lp * 1024, pb_t + lp * 32,
                att_src + (lp * 3 + 0) * 32, att_dst + (lp * 3 + 1) * 32,
                att_src + (lp * 3 + 1) * 32, att_dst + (lp * 3 + 0) * 32,
                att_src + (lp * 3 + 2) * 32, att_dst + (lp * 3 + 2) * 32,
                h_a, h_t,
                has0, adst1a, has1, adst0t, has2, adst2t,
                NA, NT, nbA16, lp == 3 ? 1 : 0);
        } else {
            agg_launch(2, NA, kw, kb, q, sc);
            combine_final_kernel<<<nbA8, blk, 0, stream>>>(agg_a, xa, ln_ag, ln_ab,
                                                           lin_w, lin_b, out, NA);
        }
    }
}

// Round 10
// 1204.510 us; speedup vs baseline: 1.5790x; 1.0533x over previous
//
#include <hip/hip_runtime.h>
#include <hip/hip_fp16.h>

#define NLAYERS 4

// ---------------- zero fill ----------------
__global__ void zero_int_kernel(int* __restrict__ p, long n) {
    long i = (long)blockIdx.x * 256 + threadIdx.x;
    long stride = (long)gridDim.x * 256;
    for (; i < n; i += stride) p[i] = 0;
}

__device__ __forceinline__ float fast_tanh(float y) {
    y = fminf(fmaxf(y, -15.f), 15.f);
    float t = __expf(2.f * y);
    return (t - 1.f) / (t + 1.f);
}

// ================= CSR build over concatenated dst space =================
// [0,NT) rel0 dsts | [NT,NT+NA) rel1 dsts | [NT+NA,NCAT) rel2 dsts
__device__ __forceinline__ int edge_row(const int* ei_in, const int* ei_out, const int* ei_sp,
                                        int E_IN, int E_OUT, int E_SP, int NT, int NA,
                                        int e, int* src) {
    if (e < E_IN) { *src = ei_in[e]; return ei_in[E_IN + e]; }
    if (e < E_IN + E_OUT) { int i = e - E_IN; *src = ei_out[i]; return NT + ei_out[E_OUT + i]; }
    int i = e - E_IN - E_OUT; *src = ei_sp[i]; return NT + NA + ei_sp[E_SP + i];
}

__global__ void hist_kernel(const int* __restrict__ ei_in, const int* __restrict__ ei_out,
                            const int* __restrict__ ei_sp, int E_IN, int E_OUT, int E_SP,
                            int NT, int NA, int* __restrict__ deg, int E_TOT) {
    int e = blockIdx.x * 256 + threadIdx.x;
    if (e >= E_TOT) return;
    int s;
    int row = edge_row(ei_in, ei_out, ei_sp, E_IN, E_OUT, E_SP, NT, NA, e, &s);
    atomicAdd(&deg[row], 1);
}

__global__ void scan1_kernel(const int* __restrict__ deg, int* __restrict__ rowptr,
                             int* __restrict__ bsum, int n) {
    __shared__ int lds[256];
    int tid = threadIdx.x;
    int base = blockIdx.x * 1024;
    int v[4];
    int mysum = 0;
    #pragma unroll
    for (int j = 0; j < 4; j++) {
        int idx = base + tid * 4 + j;
        v[j] = (idx < n) ? deg[idx] : 0;
        mysum += v[j];
    }
    lds[tid] = mysum;
    __syncthreads();
    for (int off = 1; off < 256; off <<= 1) {
        int t = (tid >= off) ? lds[tid - off] : 0;
        __syncthreads();
        lds[tid] += t;
        __syncthreads();
    }
    int excl = lds[tid] - mysum;
    if (tid == 255) bsum[blockIdx.x] = lds[tid];
    int run = excl;
    #pragma unroll
    for (int j = 0; j < 4; j++) {
        int idx = base + tid * 4 + j;
        if (idx < n) rowptr[idx] = run;
        run += v[j];
    }
}

__global__ void scan2_kernel(int* __restrict__ bsum, int nb) {
    __shared__ int lds[1024];
    int tid = threadIdx.x;
    int v = (tid < nb) ? bsum[tid] : 0;
    lds[tid] = v;
    __syncthreads();
    for (int off = 1; off < 1024; off <<= 1) {
        int t = (tid >= off) ? lds[tid - off] : 0;
        __syncthreads();
        lds[tid] += t;
        __syncthreads();
    }
    if (tid < nb) bsum[tid] = lds[tid] - v;
}

__global__ void scan3_kernel(int* __restrict__ rowptr, const int* __restrict__ bsum,
                             int* __restrict__ cursor, int n, int E) {
    int i = blockIdx.x * 256 + threadIdx.x;
    if (i < n) {
        int r = rowptr[i] + bsum[i >> 10];
        rowptr[i] = r;
        cursor[i] = r;
    }
    if (i == 0) rowptr[n] = E;
}

__global__ void scatter_kernel(const int* __restrict__ ei_in, const int* __restrict__ ei_out,
                               const int* __restrict__ ei_sp, int E_IN, int E_OUT, int E_SP,
                               int NT, int NA, int* __restrict__ cursor, int* __restrict__ col,
                               int E_TOT) {
    int e = blockIdx.x * 256 + threadIdx.x;
    if (e >= E_TOT) return;
    int s;
    int row = edge_row(ei_in, ei_out, ei_sp, E_IN, E_OUT, E_SP, NT, NA, e, &s);
    int pos = atomicAdd(&cursor[row], 1);
    col[pos] = s;
}

// ================= fused encoder + layer-0 projection (8 groups x 8 nodes / block) =================
__global__ void encproj_addr_kernel(const float* __restrict__ x,
                                    const float* __restrict__ We, const float* __restrict__ be,
                                    const float* __restrict__ Wp, const float* __restrict__ bp,
                                    const float* __restrict__ a0, const float* __restrict__ a1,
                                    float* __restrict__ xa, __half* __restrict__ h,
                                    __half* __restrict__ o0, float* __restrict__ o1,
                                    int n, int gpb) {
    __shared__ float sWe[53 * 32];
    __shared__ float sW[1024];
    __shared__ float sv[3][32];
    __shared__ float sbp[32];
    __shared__ float sx[8][56];
    __shared__ float sh[8][33];
    int tid = threadIdx.x;
    for (int i = tid; i < 53 * 32; i += 256) sWe[i] = We[i];
    for (int i = tid; i < 1024; i += 256) sW[i] = Wp[i];
    if (tid < 32) { sv[0][tid] = be[tid]; sv[1][tid] = a0[tid]; sv[2][tid] = a1[tid]; sbp[tid] = bp[tid]; }
    int local = tid >> 5, f = tid & 31;
    __syncthreads();
    for (int g = 0; g < gpb; g++) {
        int node = (blockIdx.x * gpb + g) * 8 + local;
        if (node < n) {
            for (int k = f; k < 53; k += 32) sx[local][k] = x[(size_t)node * 53 + k];
        }
        __syncthreads();
        float xe = 0.f;
        if (node < n) {
            float acc = sv[0][f];
            for (int k = 0; k < 53; k++) acc += sx[local][k] * sWe[k * 32 + f];
            xe = fmaxf(acc, 0.f);
            xa[(size_t)node * 32 + f] = xe;
        }
        sh[local][f] = xe;
        __syncthreads();
        float accp = 0.f;
        if (node < n) {
            accp = sbp[f];
            #pragma unroll
            for (int k = 0; k < 32; k++) accp += sh[local][k] * sW[k * 32 + f];
            h[(size_t)node * 32 + f] = __float2half(accp);
        }
        __syncthreads();
        sh[local][f] = accp;
        __syncthreads();
        if (node < n && f < 8) {
            int vec = f >> 2, head = f & 3;
            const float* av = sv[1 + vec];
            float dsum = 0.f;
            #pragma unroll
            for (int dd = 0; dd < 8; dd++) dsum += sh[local][head * 8 + dd] * av[head * 8 + dd];
            if (vec == 0) o0[(size_t)node * 4 + head] = __float2half(dsum);
            else o1[(size_t)node * 4 + head] = dsum;
        }
        __syncthreads();
    }
}

__global__ void encproj_tx_kernel(const float* __restrict__ x,
                                  const float* __restrict__ We, const float* __restrict__ be,
                                  const float* __restrict__ Wp, const float* __restrict__ bp,
                                  const float* __restrict__ a0, const float* __restrict__ a1,
                                  const float* __restrict__ a2, const float* __restrict__ a3,
                                  float* __restrict__ xt, __half* __restrict__ h,
                                  __half* __restrict__ o0, float* __restrict__ o1,
                                  __half* __restrict__ o2, float* __restrict__ o3,
                                  int n, int gpb) {
    __shared__ float sWe[6 * 32];
    __shared__ float sW[1024];
    __shared__ float sv[5][32];
    __shared__ float sbp[32];
    __shared__ float sx[8][8];
    __shared__ float sh[8][33];
    int tid = threadIdx.x;
    for (int i = tid; i < 6 * 32; i += 256) sWe[i] = We[i];
    for (int i = tid; i < 1024; i += 256) sW[i] = Wp[i];
    if (tid < 32) {
        sv[0][tid] = be[tid]; sv[1][tid] = a0[tid]; sv[2][tid] = a1[tid];
        sv[3][tid] = a2[tid]; sv[4][tid] = a3[tid]; sbp[tid] = bp[tid];
    }
    int local = tid >> 5, f = tid & 31;
    __syncthreads();
    for (int g = 0; g < gpb; g++) {
        int node = (blockIdx.x * gpb + g) * 8 + local;
        if (node < n && f < 6) sx[local][f] = x[(size_t)node * 6 + f];
        __syncthreads();
        float xe = 0.f;
        if (node < n) {
            float acc = sv[0][f];
            #pragma unroll
            for (int k = 0; k < 6; k++) acc += sx[local][k] * sWe[k * 32 + f];
            xe = fmaxf(acc, 0.f);
            xt[(size_t)node * 32 + f] = xe;
        }
        sh[local][f] = xe;
        __syncthreads();
        float accp = 0.f;
        if (node < n) {
            accp = sbp[f];
            #pragma unroll
            for (int k = 0; k < 32; k++) accp += sh[local][k] * sW[k * 32 + f];
            h[(size_t)node * 32 + f] = __float2half(accp);
        }
        __syncthreads();
        sh[local][f] = accp;
        __syncthreads();
        if (node < n && f < 16) {
            int vec = f >> 2, head = f & 3;
            const float* av = sv[1 + vec];
            float dsum = 0.f;
            #pragma unroll
            for (int dd = 0; dd < 8; dd++) dsum += sh[local][head * 8 + dd] * av[head * 8 + dd];
            if (vec == 0) o0[(size_t)node * 4 + head] = __float2half(dsum);
            else if (vec == 1) o1[(size_t)node * 4 + head] = dsum;
            else if (vec == 2) o2[(size_t)node * 4 + head] = __float2half(dsum);
            else o3[(size_t)node * 4 + head] = dsum;
        }
        __syncthreads();
    }
}

// ================= merged CSR aggregation (all rels) + fused semantic score =================
// 8 lanes/dst; packed hfma2 accumulation; clamped unroll-4; fp16 asrc; 32-bit indexing.
__global__ void agg_all_kernel(
    const int* __restrict__ rowptr, const int* __restrict__ col,
    const __half* __restrict__ h_a, const __half* __restrict__ h_t,
    const __half* __restrict__ asrc0, const float* __restrict__ adst0,
    const __half* __restrict__ asrc1, const float* __restrict__ adst1,
    const __half* __restrict__ asrc2, const float* __restrict__ adst2,
    __half* __restrict__ agg_t0, __half* __restrict__ agg_a, __half* __restrict__ agg_t2,
    const float* __restrict__ kw, const float* __restrict__ kb, const float* __restrict__ q,
    float* __restrict__ scoreOut, int NT, int NA, int mode, int nRows) {
    __shared__ float sW[1024];
    __shared__ float sb[32];
    __shared__ float sq[32];
    __shared__ float sScore[2];
    int tid = threadIdx.x;
    bool doScore = (mode != 2);
    if (doScore) {
        for (int i = tid; i < 1024; i += 256) sW[i] = kw[i];
        if (tid < 32) { sb[tid] = kb[tid]; sq[tid] = q[tid]; }
        if (tid < 2) sScore[tid] = 0.f;
        __syncthreads();
    }
    int lane = tid & 7;
    int head = lane >> 1;
    int f0 = lane * 4;
    long stride = (long)gridDim.x * 32;
    for (long gi = (long)blockIdx.x * 32 + (tid >> 3); gi < (long)nRows; gi += stride) {
        int row;
        if (mode == 0) row = (int)gi;
        else if (mode == 1) row = (gi < NT) ? (int)gi : (int)(gi + NA);
        else row = NT + (int)gi;
        int rel, dst;
        const __half* h; const __half* asrc; const float* adp; __half* agg;
        if (row < NT)           { rel = 0; dst = row;           h = h_a; asrc = asrc0; adp = adst0; agg = agg_t0; }
        else if (row < NT + NA) { rel = 1; dst = row - NT;      h = h_t; asrc = asrc1; adp = adst1; agg = agg_a; }
        else                    { rel = 2; dst = row - NT - NA; h = h_t; asrc = asrc2; adp = adst2; agg = agg_t2; }
        float ad = adp[dst * 4 + head];
        int e0 = rowptr[row], e1 = rowptr[row + 1];
        __half2 acc0 = __floats2half2_rn(0.f, 0.f);
        __half2 acc1 = acc0;
        float den = 0.f;
        for (int e = e0; e < e1; e += 4) {
            int s0 = col[e];
            int s1 = (e + 1 < e1) ? col[e + 1] : s0;
            int s2 = (e + 2 < e1) ? col[e + 2] : s0;
            int s3 = (e + 3 < e1) ? col[e + 3] : s0;
            float as0 = __half2float(asrc[s0 * 4 + head]);
            float as1 = __half2float(asrc[s1 * 4 + head]);
            float as2 = __half2float(asrc[s2 * 4 + head]);
            float as3 = __half2float(asrc[s3 * 4 + head]);
            float2 r0 = *(const float2*)(h + s0 * 32 + f0);
            float2 r1 = *(const float2*)(h + s1 * 32 + f0);
            float2 r2 = *(const float2*)(h + s2 * 32 + f0);
            float2 r3 = *(const float2*)(h + s3 * 32 + f0);
            float t0 = as0 + ad; t0 = t0 > 0.f ? t0 : 0.2f * t0;
            float t1 = as1 + ad; t1 = t1 > 0.f ? t1 : 0.2f * t1;
            float t2 = as2 + ad; t2 = t2 > 0.f ? t2 : 0.2f * t2;
            float t3 = as3 + ad; t3 = t3 > 0.f ? t3 : 0.2f * t3;
            float ex0 = __expf(t0);
            float ex1 = (e + 1 < e1) ? __expf(t1) : 0.f;
            float ex2 = (e + 2 < e1) ? __expf(t2) : 0.f;
            float ex3 = (e + 3 < e1) ? __expf(t3) : 0.f;
            den += (ex0 + ex1) + (ex2 + ex3);
            __half2 eh0 = __float2half2_rn(ex0), eh1 = __float2half2_rn(ex1);
            __half2 eh2 = __float2half2_rn(ex2), eh3 = __float2half2_rn(ex3);
            acc0 = __hfma2(eh0, *(__half2*)&r0.x, acc0);
            acc1 = __hfma2(eh0, *(__half2*)&r0.y, acc1);
            acc0 = __hfma2(eh1, *(__half2*)&r1.x, acc0);
            acc1 = __hfma2(eh1, *(__half2*)&r1.y, acc1);
            acc0 = __hfma2(eh2, *(__half2*)&r2.x, acc0);
            acc1 = __hfma2(eh2, *(__half2*)&r2.y, acc1);
            acc0 = __hfma2(eh3, *(__half2*)&r3.x, acc0);
            acc1 = __hfma2(eh3, *(__half2*)&r3.y, acc1);
        }
        float r = 1.f / (den + 1e-16f);
        float2 a0 = __half22float2(acc0), a1 = __half22float2(acc1);
        float v0 = a0.x * r, v1 = a0.y * r, v2 = a1.x * r, v3 = a1.y * r;
        float2 opack;
        __half2 o0 = __floats2half2_rn(v0, v1), o1 = __floats2half2_rn(v2, v3);
        opack.x = *(float*)&o0; opack.y = *(float*)&o1;
        *(float2*)(agg + dst * 32 + f0) = opack;
        if (doScore && rel != 1) {
            float rv0 = fmaxf(v0, 0.f), rv1 = fmaxf(v1, 0.f);
            float rv2 = fmaxf(v2, 0.f), rv3 = fmaxf(v3, 0.f);
            float y0 = sb[f0], y1 = sb[f0 + 1], y2 = sb[f0 + 2], y3 = sb[f0 + 3];
            #pragma unroll
            for (int g = 0; g < 8; g++) {
                float c0 = __shfl(rv0, g, 8);
                float c1 = __shfl(rv1, g, 8);
                float c2 = __shfl(rv2, g, 8);
                float c3 = __shfl(rv3, g, 8);
                int kb4 = g * 4;
                y0 += c0 * sW[(kb4 + 0) * 32 + f0] + c1 * sW[(kb4 + 1) * 32 + f0]
                    + c2 * sW[(kb4 + 2) * 32 + f0] + c3 * sW[(kb4 + 3) * 32 + f0];
                y1 += c0 * sW[(kb4 + 0) * 32 + f0 + 1] + c1 * sW[(kb4 + 1) * 32 + f0 + 1]
                    + c2 * sW[(kb4 + 2) * 32 + f0 + 1] + c3 * sW[(kb4 + 3) * 32 + f0 + 1];
                y2 += c0 * sW[(kb4 + 0) * 32 + f0 + 2] + c1 * sW[(kb4 + 1) * 32 + f0 + 2]
                    + c2 * sW[(kb4 + 2) * 32 + f0 + 2] + c3 * sW[(kb4 + 3) * 32 + f0 + 2];
                y3 += c0 * sW[(kb4 + 0) * 32 + f0 + 3] + c1 * sW[(kb4 + 1) * 32 + f0 + 3]
                    + c2 * sW[(kb4 + 2) * 32 + f0 + 3] + c3 * sW[(kb4 + 3) * 32 + f0 + 3];
            }
            float sacc = sq[f0] * fast_tanh(y0) + sq[f0 + 1] * fast_tanh(y1)
                       + sq[f0 + 2] * fast_tanh(y2) + sq[f0 + 3] * fast_tanh(y3);
            #pragma unroll
            for (int m = 1; m < 8; m <<= 1) sacc += __shfl_xor(sacc, m, 8);
            if (lane == 0) atomicAdd(&sScore[rel == 2 ? 1 : 0], sacc);
        }
    }
    if (doScore) {
        __syncthreads();
        if (tid < 2) unsafeAtomicAdd(scoreOut + tid, sScore[tid]);
    }
}

// ================= fused combine + next-layer projection (4 groups x 16 nodes / block) =================
__global__ void combineproj_kernel(
    const __half* __restrict__ agg_a, const __half* __restrict__ agg_t0, const __half* __restrict__ agg_t2,
    float* __restrict__ xa, float* __restrict__ xt,
    const float* __restrict__ ln_ag, const float* __restrict__ ln_ab,
    const float* __restrict__ ln_tg, const float* __restrict__ ln_tb,
    const float* __restrict__ scores, float invNT,
    const float* __restrict__ Wa, const float* __restrict__ Ba,
    const float* __restrict__ Wt, const float* __restrict__ Bt,
    const float* __restrict__ as0, const float* __restrict__ ad1,
    const float* __restrict__ as1, const float* __restrict__ ad0,
    const float* __restrict__ as2, const float* __restrict__ ad2,
    __half* __restrict__ h_a, __half* __restrict__ h_t,
    __half* __restrict__ o_as0, float* __restrict__ o_ad1,
    __half* __restrict__ o_as1, float* __restrict__ o_ad0,
    __half* __restrict__ o_as2, float* __restrict__ o_ad2,
    int NA_, int NT_, int nbAcp, int gpb, int lastProj) {
    __shared__ float sW[1024];
    __shared__ float sv[5][32];
    __shared__ float sbp[32];
    __shared__ float sh[16][33];
    int tid = threadIdx.x;
    bool isA = blockIdx.x < nbAcp;
    const float* W = isA ? Wa : Wt;
    for (int i = tid; i < 1024; i += 256) sW[i] = W[i];
    if (tid < 32) {
        sbp[tid] = (isA ? Ba : Bt)[tid];
        sv[1][tid] = (isA ? as0 : as1)[tid];
        sv[2][tid] = (isA ? ad1 : ad0)[tid];
        if (!isA) { sv[3][tid] = as2[tid]; sv[4][tid] = ad2[tid]; }
    }
    int local = tid >> 5, f = tid & 31;
    int n = isA ? NA_ : NT_;
    float wsem0 = 0.f, wsem2 = 0.f;
    if (!isA) {
        float s0 = scores[0] * invNT, s2 = scores[1] * invNT;
        float mx = fmaxf(s0, s2);
        float e0 = __expf(s0 - mx), e2 = __expf(s2 - mx);
        float inv_s = 1.f / (e0 + e2);
        wsem0 = e0 * inv_s; wsem2 = e2 * inv_s;
    }
    const float* lng = isA ? ln_ag : ln_tg;
    const float* lnb = isA ? ln_ab : ln_tb;
    float gln = lng[f], bln = lnb[f];
    __syncthreads();
    int blockBase = (isA ? blockIdx.x : blockIdx.x - nbAcp) * gpb * 16;
    for (int g = 0; g < gpb; g++) {
        int base = blockBase + g * 16;
        int node0 = base + local, node1 = base + local + 8;
        float ln0 = 0.f, ln1 = 0.f;
        if (node0 < n) {
            float v;
            if (isA) {
                v = fmaxf(__half2float(agg_a[(size_t)node0 * 32 + f]), 0.f) + xa[(size_t)node0 * 32 + f];
            } else {
                float a0 = fmaxf(__half2float(agg_t0[(size_t)node0 * 32 + f]), 0.f);
                float a2 = fmaxf(__half2float(agg_t2[(size_t)node0 * 32 + f]), 0.f);
                v = fmaxf(wsem0 * a0 + wsem2 * a2, 0.f) + xt[(size_t)node0 * 32 + f];
            }
            float m = v;
            #pragma unroll
            for (int mask = 1; mask < 32; mask <<= 1) m += __shfl_xor(m, mask, 64);
            m *= (1.f / 32.f);
            float d = v - m;
            float var = d * d;
            #pragma unroll
            for (int mask = 1; mask < 32; mask <<= 1) var += __shfl_xor(var, mask, 64);
            var *= (1.f / 32.f);
            ln0 = d * (1.f / sqrtf(var + 1e-5f)) * gln + bln;
            if (isA) xa[(size_t)node0 * 32 + f] = ln0;
            else if (!lastProj) xt[(size_t)node0 * 32 + f] = ln0;
        }
        if (node1 < n) {
            float v;
            if (isA) {
                v = fmaxf(__half2float(agg_a[(size_t)node1 * 32 + f]), 0.f) + xa[(size_t)node1 * 32 + f];
            } else {
                float a0 = fmaxf(__half2float(agg_t0[(size_t)node1 * 32 + f]), 0.f);
                float a2 = fmaxf(__half2float(agg_t2[(size_t)node1 * 32 + f]), 0.f);
                v = fmaxf(wsem0 * a0 + wsem2 * a2, 0.f) + xt[(size_t)node1 * 32 + f];
            }
            float m = v;
            #pragma unroll
            for (int mask = 1; mask < 32; mask <<= 1) m += __shfl_xor(m, mask, 64);
            m *= (1.f / 32.f);
            float d = v - m;
            float var = d * d;
            #pragma unroll
            for (int mask = 1; mask < 32; mask <<= 1) var += __shfl_xor(var, mask, 64);
            var *= (1.f / 32.f);
            ln1 = d * (1.f / sqrtf(var + 1e-5f)) * gln + bln;
            if (isA) xa[(size_t)node1 * 32 + f] = ln1;
            else if (!lastProj) xt[(size_t)node1 * 32 + f] = ln1;
        }
        sh[local][f] = ln0;
        sh[local + 8][f] = ln1;
        __syncthreads();
        float acc0 = sbp[f], acc1 = sbp[f];
        #pragma unroll
        for (int k = 0; k < 32; k++) {
            float w = sW[k * 32 + f];
            acc0 += sh[local][k] * w;
            acc1 += sh[local + 8][k] * w;
        }
        bool writeH = (!isA || !lastProj);
        __half* hptr = isA ? h_a : h_t;
        if (writeH) {
            if (node0 < n) hptr[(size_t)node0 * 32 + f] = __float2half(acc0);
            if (node1 < n) hptr[(size_t)node1 * 32 + f] = __float2half(acc1);
        }
        __syncthreads();
        sh[local][f] = acc0;
        sh[local + 8][f] = acc1;
        __syncthreads();
        int nvec = isA ? 8 : 16;
        if (f < nvec) {
            int vec = f >> 2, head = f & 3;
            bool need = !lastProj || (isA ? (vec == 1) : (vec == 0));
            if (need) {
                const float* av = sv[1 + vec];
                float d0 = 0.f, d1 = 0.f;
                #pragma unroll
                for (int dd = 0; dd < 8; dd++) {
                    float a = av[head * 8 + dd];
                    d0 += sh[local][head * 8 + dd] * a;
                    d1 += sh[local + 8][head * 8 + dd] * a;
                }
                bool isHalf = isA ? (vec == 0) : (vec == 0 || vec == 2);
                if (isHalf) {
                    __half* op = isA ? o_as0 : (vec == 0 ? o_as1 : o_as2);
                    if (node0 < n) op[(size_t)node0 * 4 + head] = __float2half(d0);
                    if (node1 < n) op[(size_t)node1 * 4 + head] = __float2half(d1);
                } else {
                    float* op = isA ? o_ad1 : (vec == 1 ? o_ad0 : o_ad2);
                    if (node0 < n) op[(size_t)node0 * 4 + head] = d0;
                    if (node1 < n) op[(size_t)node1 * 4 + head] = d1;
                }
            }
        }
        __syncthreads();
    }
}

// ================= layer-3 combine_addr + output head =================
__global__ void combine_final_kernel(const __half* __restrict__ agg_a, const float* __restrict__ xa,
                                     const float* __restrict__ g, const float* __restrict__ bt,
                                     const float* __restrict__ lw, const float* __restrict__ lb,
                                     float* __restrict__ out, int n) {
    int tid = threadIdx.x;
    int local = tid >> 5, f = tid & 31;
    int node = blockIdx.x * 8 + local;
    if (node >= n) return;
    float a = __half2float(agg_a[(size_t)node * 32 + f]);
    float v = fmaxf(a, 0.f) + xa[(size_t)node * 32 + f];
    float m = v;
    #pragma unroll
    for (int mask = 1; mask < 32; mask <<= 1) m += __shfl_xor(m, mask, 64);
    m *= (1.f / 32.f);
    float d = v - m;
    float var = d * d;
    #pragma unroll
    for (int mask = 1; mask < 32; mask <<= 1) var += __shfl_xor(var, mask, 64);
    var *= (1.f / 32.f);
    float inv = 1.f / sqrtf(var + 1e-5f);
    float ln = d * inv * g[f] + bt[f];
    float p0 = ln * lw[f * 2 + 0];
    float p1 = ln * lw[f * 2 + 1];
    #pragma unroll
    for (int mask = 1; mask < 32; mask <<= 1) {
        p0 += __shfl_xor(p0, mask, 64);
        p1 += __shfl_xor(p1, mask, 64);
    }
    if (f == 0) {
        out[(size_t)node * 2 + 0] = p0 + lb[0];
        out[(size_t)node * 2 + 1] = p1 + lb[1];
    }
}

extern "C" void kernel_launch(void* const* d_in, const int* in_sizes, int n_in,
                              void* d_out, int out_size, void* d_ws, size_t ws_size,
                              hipStream_t stream) {
    const float* x_addr = (const float*)d_in[0];
    const float* x_tx   = (const float*)d_in[1];
    const int* ei_in    = (const int*)d_in[2];
    const int* ei_out   = (const int*)d_in[3];
    const int* ei_sp    = (const int*)d_in[4];
    const float* enc_w_addr = (const float*)d_in[5];
    const float* enc_b_addr = (const float*)d_in[6];
    const float* enc_w_tx   = (const float*)d_in[7];
    const float* enc_b_tx   = (const float*)d_in[8];
    const float* ln_ag = (const float*)d_in[9];
    const float* ln_ab = (const float*)d_in[10];
    const float* ln_tg = (const float*)d_in[11];
    const float* ln_tb = (const float*)d_in[12];
    const float* pw_a = (const float*)d_in[13];
    const float* pb_a = (const float*)d_in[14];
    const float* pw_t = (const float*)d_in[15];
    const float* pb_t = (const float*)d_in[16];
    const float* att_src = (const float*)d_in[17];
    const float* att_dst = (const float*)d_in[18];
    const float* klw = (const float*)d_in[19];
    const float* klb = (const float*)d_in[20];
    const float* qv  = (const float*)d_in[21];
    const float* lin_w = (const float*)d_in[22];
    const float* lin_b = (const float*)d_in[23];
    float* out = (float*)d_out;

    const int NA = in_sizes[0] / 53;
    const int NT = in_sizes[1] / 6;
    const int E_IN = in_sizes[2] / 2;
    const int E_OUT = in_sizes[3] / 2;
    const int E_SP = in_sizes[4] / 2;
    const int E_TOT = E_IN + E_OUT + E_SP;
    const int NCAT = NT + NA + NT;

    size_t off = 0;
    float* base = (float*)d_ws;
    auto alloc = [&](size_t nfloats) {
        float* p = base + off;
        off += (nfloats + 63) & ~(size_t)63;
        return p;
    };
    float* xa      = alloc((size_t)NA * 32);
    float* xt      = alloc((size_t)NT * 32);
    float* agg_a_f = alloc((size_t)NA * 16);
    float* agg_t0f = alloc((size_t)NT * 16);
    float* agg_t2f = alloc((size_t)NT * 16);
    float* h_t_f   = alloc((size_t)NT * 16);
    float* asrc0a  = alloc((size_t)NA * 2);   // fp16 x4 per node
    float* adst1a  = alloc((size_t)NA * 4);
    float* asrc1t  = alloc((size_t)NT * 2);   // fp16
    float* adst0t  = alloc((size_t)NT * 4);
    float* asrc2t  = alloc((size_t)NT * 2);   // fp16
    float* adst2t  = alloc((size_t)NT * 4);
    int* rowptrAll = (int*)alloc((size_t)NCAT + 64);
    int* colAll    = (int*)alloc((size_t)E_TOT);
    size_t tmp_span = (((size_t)NCAT + 63) & ~(size_t)63) + 1088 + 64;
    int* tmp       = (int*)alloc((size_t)NCAT);
    int* bsum      = (int*)alloc(1088);
    float* scores  = alloc(64);

    size_t ha_floats = (((size_t)NA * 16) + 63) & ~(size_t)63;
    bool roomy = ((off + ha_floats) * sizeof(float)) <= ws_size;
    float* h_a_f = roomy ? alloc((size_t)NA * 16) : agg_a_f;

    __half* agg_a  = (__half*)agg_a_f;
    __half* agg_t0 = (__half*)agg_t0f;
    __half* agg_t2 = (__half*)agg_t2f;
    __half* h_t    = (__half*)h_t_f;
    __half* h_a    = (__half*)h_a_f;
    __half* has0   = (__half*)asrc0a;
    __half* has1   = (__half*)asrc1t;
    __half* has2   = (__half*)asrc2t;

    dim3 blk(256);
    const int GPB_E = 8;    // 64 nodes/block for encproj
    const int GPB_C = 4;    // 64 nodes/block for combineproj
    int nbA8 = (NA + 7) / 8;
    int nbAe = (NA + 8 * GPB_E - 1) / (8 * GPB_E);
    int nbTe = (NT + 8 * GPB_E - 1) / (8 * GPB_E);
    int nbAcp = (NA + 16 * GPB_C - 1) / (16 * GPB_C);
    int nbTcp = (NT + 16 * GPB_C - 1) / (16 * GPB_C);
    int nbE = (E_TOT + 255) / 256;
    int nbScan = (NCAT + 1023) / 1024;

    // ---- CSR build (once, reused by all layers) ----
    zero_int_kernel<<<2048, blk, 0, stream>>>(tmp, (long)tmp_span);
    hist_kernel<<<nbE, blk, 0, stream>>>(ei_in, ei_out, ei_sp, E_IN, E_OUT, E_SP, NT, NA, tmp, E_TOT);
    scan1_kernel<<<nbScan, blk, 0, stream>>>(tmp, rowptrAll, bsum, NCAT);
    scan2_kernel<<<1, 1024, 0, stream>>>(bsum, nbScan);
    scan3_kernel<<<(NCAT + 255) / 256, blk, 0, stream>>>(rowptrAll, bsum, tmp, NCAT, E_TOT);
    scatter_kernel<<<nbE, blk, 0, stream>>>(ei_in, ei_out, ei_sp, E_IN, E_OUT, E_SP, NT, NA, tmp, colAll, E_TOT);

    // ---- fused encoder + layer-0 projection ----
    encproj_addr_kernel<<<nbAe, blk, 0, stream>>>(
        x_addr, enc_w_addr, enc_b_addr, pw_a, pb_a,
        att_src + 0 * 32, att_dst + 1 * 32,
        xa, h_a, has0, adst1a, NA, GPB_E);
    encproj_tx_kernel<<<nbTe, blk, 0, stream>>>(
        x_tx, enc_w_tx, enc_b_tx, pw_t, pb_t,
        att_src + 1 * 32, att_dst + 0 * 32, att_src + 2 * 32, att_dst + 2 * 32,
        xt, h_t, has1, adst0t, has2, adst2t, NT, GPB_E);

    auto agg_launch = [&](int mode, int nRows, const float* kw, const float* kb,
                          const float* q, float* sc) {
        int blocks = (nRows + 31) / 32;
        if (blocks > 2048) blocks = 2048;
        agg_all_kernel<<<blocks, blk, 0, stream>>>(
            rowptrAll, colAll, h_a, h_t,
            has0, adst0t, has1, adst1a, has2, adst2t,
            agg_t0, agg_a, agg_t2, kw, kb, q, sc, NT, NA, mode, nRows);
    };

    for (int l = 0; l < NLAYERS; l++) {
        bool last = (l == NLAYERS - 1);
        const float* kw = klw + l * 1024;
        const float* kb = klb + l * 32;
        const float* q  = qv + l * 32;
        float* sc = scores + 2 * l;
        if (!last) {
            if (roomy) {
                agg_launch(0, NCAT, kw, kb, q, sc);
            } else {
                agg_launch(1, 2 * NT, kw, kb, q, sc);
                agg_launch(2, NA, kw, kb, q, sc);
            }
            int lp = l + 1;
            combineproj_kernel<<<nbAcp + nbTcp, blk, 0, stream>>>(
                agg_a, agg_t0, agg_t2, xa, xt,
                ln_ag, ln_ab, ln_tg, ln_tb,
                sc, 1.0f / (float)NT,
                pw_a + lp * 1024, pb_a + lp * 32, pw_t + lp * 1024, pb_t + lp * 32,
                att_src + (lp * 3 + 0) * 32, att_dst + (lp * 3 + 1) * 32,
                att_src + (lp * 3 + 1) * 32, att_dst + (lp * 3 + 0) * 32,
                att_src + (lp * 3 + 2) * 32, att_dst + (lp * 3 + 2) * 32,
                h_a, h_t,
                has0, adst1a, has1, adst0t, has2, adst2t,
                NA, NT, nbAcp, GPB_C, lp == 3 ? 1 : 0);
        } else {
            agg_launch(2, NA, kw, kb, q, sc);
            combine_final_kernel<<<nbA8, blk, 0, stream>>>(agg_a, xa, ln_ag, ln_ab,
                                                           lin_w, lin_b, out, NA);
        }
    }
}